// Round 12
// baseline (301.977 us; speedup 1.0000x reference)
//
#include <hip/hip_runtime.h>
#include <hip/hip_bf16.h>
#include <stdint.h>

#define N_NODES 100000
constexpr float BN_EPS = 1e-5f;

typedef __bf16 bf16x8 __attribute__((ext_vector_type(8)));
typedef float f32x4 __attribute__((ext_vector_type(4)));

__device__ inline unsigned int pk2(float a, float b) {
    __bf16 x = (__bf16)a, y = (__bf16)b;
    return (unsigned int)__builtin_bit_cast(unsigned short, x) |
           ((unsigned int)__builtin_bit_cast(unsigned short, y) << 16);
}

// ---------------- K0: weight prep + BN affine prep ----------------
__global__ __launch_bounds__(256) void k_wbn(int wpB,
                                             const float* __restrict__ W1l,
                                             const float* __restrict__ W1r,
                                             const float* __restrict__ W2l,
                                             const float* __restrict__ W2r,
                                             __bf16* __restrict__ Wt1hi,
                                             __bf16* __restrict__ Wt1lo,
                                             __bf16* __restrict__ Wt2hi,
                                             __bf16* __restrict__ Wt2lo,
                                             const float* __restrict__ b1l,
                                             const float* __restrict__ g1,
                                             const float* __restrict__ be1,
                                             const float* __restrict__ m1,
                                             const float* __restrict__ v1,
                                             const float* __restrict__ b2l,
                                             const float* __restrict__ g2,
                                             const float* __restrict__ be2,
                                             const float* __restrict__ m2,
                                             const float* __restrict__ v2,
                                             float* __restrict__ bn) {
    if ((int)blockIdx.x < wpB) {
        int idx = blockIdx.x * 256 + threadIdx.x;
        const float* W; __bf16 *Whi, *Wlo; int halfN, lidx;
        if (idx < 2 * 128 * 128) {
            lidx = idx; halfN = 128; Whi = Wt1hi; Wlo = Wt1lo;
            W = ((lidx >> 7) < 128) ? W1l : W1r;
        } else {
            lidx = idx - 2 * 128 * 128;
            if (lidx >= 2 * 64 * 128) return;
            halfN = 64; Whi = Wt2hi; Wlo = Wt2lo;
            W = ((lidx >> 7) < 64) ? W2l : W2r;
        }
        int c = lidx >> 7, k = lidx & 127;
        int cc = (c < halfN) ? c : c - halfN;
        float v = W[(size_t)k * halfN + cc];
        __bf16 h = (__bf16)v;
        Whi[lidx] = h;
        Wlo[lidx] = (__bf16)(v - (float)h);
        return;
    }
    int t = threadIdx.x;
    if (t < 128) {
        float S = g1[t] * rsqrtf(v1[t] + BN_EPS);
        bn[t] = S;
        bn[128 + t] = (b1l[t] - m1[t]) * S + be1[t];
    } else if (t < 192) {
        int f = t - 128;
        float S = g2[f] * rsqrtf(v2[f] + BN_EPS);
        bn[256 + f] = S;
        bn[320 + f] = (b2l[f] - m2[f]) * S + be2[f];
    }
}

// ---------------- bf16x3 MFMA GEMM body (f32 A), B staged in LDS ----------
template <int SPLITC>
__device__ void mfma_body(const float* __restrict__ A,
                          const __bf16* __restrict__ Wthi,
                          const __bf16* __restrict__ Wtlo,
                          __bf16* __restrict__ Cl, float* __restrict__ Cr,
                          int M, int bid) {
    constexpr int K = 128;
    __shared__ __bf16 sB[2][128][40];     // 20 KB
    const int tid = threadIdx.x;
    const int lane = tid & 63;
    const int wave = tid >> 6;
    const int row0 = bid * 128 + wave * 32;
    const int rlo = lane & 15;
    const int rhi = lane >> 4;

    const int sc = tid >> 1;
    const int sseg = (tid & 1) * 16;

    f32x4 acc[4][2][2] = {};

    for (int k0 = 0; k0 < K; k0 += 32) {
        if (k0) __syncthreads();
        {
            const __bf16* gh = Wthi + (size_t)sc * K + k0 + sseg;
            const __bf16* gl = Wtlo + (size_t)sc * K + k0 + sseg;
            *(bf16x8*)(&sB[0][sc][sseg])     = *(const bf16x8*)gh;
            *(bf16x8*)(&sB[0][sc][sseg + 8]) = *(const bf16x8*)(gh + 8);
            *(bf16x8*)(&sB[1][sc][sseg])     = *(const bf16x8*)gl;
            *(bf16x8*)(&sB[1][sc][sseg + 8]) = *(const bf16x8*)(gl + 8);
        }
        bf16x8 ahi[2], alo[2];
        #pragma unroll
        for (int wr = 0; wr < 2; ++wr) {
            int row = row0 + wr * 16 + rlo;
            row = row < M ? row : M - 1;
            const float* ap = A + (size_t)row * K + k0 + rhi * 8;
            float4 v0 = *(const float4*)ap;
            float4 v1 = *(const float4*)(ap + 4);
            float vv[8] = {v0.x, v0.y, v0.z, v0.w, v1.x, v1.y, v1.z, v1.w};
            #pragma unroll
            for (int i = 0; i < 8; ++i) {
                __bf16 h = (__bf16)vv[i];
                ahi[wr][i] = h;
                alo[wr][i] = (__bf16)(vv[i] - (float)h);
            }
        }
        __syncthreads();
        #pragma unroll
        for (int cs = 0; cs < 4; ++cs) {
            #pragma unroll
            for (int cf = 0; cf < 2; ++cf) {
                int c = cs * 32 + cf * 16 + rlo;
                bf16x8 bhi = *(const bf16x8*)(&sB[0][c][rhi * 8]);
                bf16x8 blo = *(const bf16x8*)(&sB[1][c][rhi * 8]);
                #pragma unroll
                for (int wr = 0; wr < 2; ++wr) {
                    f32x4 a = acc[cs][wr][cf];
                    a = __builtin_amdgcn_mfma_f32_16x16x32_bf16(ahi[wr], bhi, a, 0, 0, 0);
                    a = __builtin_amdgcn_mfma_f32_16x16x32_bf16(ahi[wr], blo, a, 0, 0, 0);
                    a = __builtin_amdgcn_mfma_f32_16x16x32_bf16(alo[wr], bhi, a, 0, 0, 0);
                    acc[cs][wr][cf] = a;
                }
            }
        }
    }

    #pragma unroll
    for (int cs = 0; cs < 4; ++cs)
        #pragma unroll
        for (int cf = 0; cf < 2; ++cf) {
            int c = cs * 32 + cf * 16 + rlo;
            #pragma unroll
            for (int wr = 0; wr < 2; ++wr)
                #pragma unroll
                for (int r = 0; r < 4; ++r) {
                    int row = row0 + wr * 16 + rhi * 4 + r;
                    if (row < M) {
                        float val = acc[cs][wr][cf][r];
                        if (c < SPLITC)
                            Cl[(size_t)row * SPLITC + c] = (__bf16)val;
                        else
                            Cr[(size_t)row * (128 - SPLITC) + (c - SPLITC)] = val;
                    }
                }
        }
}

// ---------------- K1: fused edge-prep (first) + layer-1 GEMM half1 --------
// deg padded: 16 ints (64 B) per node -> no inter-node line contention
__global__ __launch_bounds__(256) void k_prep_gemm(const unsigned int* __restrict__ w,
                                                   int E, int* __restrict__ idx32,
                                                   int* __restrict__ rank,
                                                   int* __restrict__ deg,
                                                   int prepB,
                                                   const float* __restrict__ A,
                                                   const __bf16* __restrict__ Wthi,
                                                   const __bf16* __restrict__ Wtlo,
                                                   __bf16* __restrict__ Cl, int M) {
    int bid = blockIdx.x;
    if (bid < prepB) {
        unsigned int wv = w[1 + 2 * (threadIdx.x & 63)];
        int f = __any(wv != 0);        // 1 => int32, 0 => int64
        int e = bid * 256 + threadIdx.x;
        if (e >= E) return;
        int s = (int)(f ? w[e] : w[2 * (size_t)e]);
        int d = (int)(f ? w[E + e] : w[2 * ((size_t)E + e)]);
        idx32[e] = s;
        idx32[E + e] = d;
        rank[e] = atomicAdd(&deg[d << 4], 1);
        return;
    }
    mfma_body<128>(A, Wthi, Wtlo, Cl, nullptr, M, bid - prepB);
}

// ---------------- scans (deg strided by 16) ----------------
__global__ __launch_bounds__(256) void k_scan1(const int* __restrict__ deg,
                                               int* __restrict__ offs,
                                               int* __restrict__ bsum, int n) {
    __shared__ int s[256];
    int t = threadIdx.x;
    int i = blockIdx.x * 256 + t;
    int v = (i < n) ? deg[i << 4] : 0;
    s[t] = v;
    __syncthreads();
    for (int off = 1; off < 256; off <<= 1) {
        int add = (t >= off) ? s[t - off] : 0;
        __syncthreads();
        s[t] += add;
        __syncthreads();
    }
    if (i < n) offs[i] = s[t] - v;
    if (t == 255) bsum[blockIdx.x] = s[255];
}

__global__ __launch_bounds__(256) void k_scan2(int* __restrict__ bsum, int nb) {
    __shared__ int s[256];
    __shared__ int carry;
    int t = threadIdx.x;
    if (t == 0) carry = 0;
    __syncthreads();
    for (int base = 0; base < nb; base += 256) {
        int i = base + t;
        int v = (i < nb) ? bsum[i] : 0;
        s[t] = v;
        __syncthreads();
        for (int off = 1; off < 256; off <<= 1) {
            int add = (t >= off) ? s[t - off] : 0;
            __syncthreads();
            s[t] += add;
            __syncthreads();
        }
        if (i < nb) bsum[i] = s[t] - v + carry;
        __syncthreads();
        if (t == 0) carry += s[255];
        __syncthreads();
    }
}

__global__ void k_scan3(int* __restrict__ offs, const int* __restrict__ bsum,
                        int n, int E) {
    int i = blockIdx.x * blockDim.x + threadIdx.x;
    if (i < n) offs[i] += bsum[i >> 8];
    if (i == 0) offs[n] = E;
}

// ---------------- K3: fused layer-1 GEMM half2 (bf16 out) + CSR scatter ----
__global__ __launch_bounds__(256) void k_gemm_scat(const float* __restrict__ A,
                                                   const __bf16* __restrict__ Wthi,
                                                   const __bf16* __restrict__ Wtlo,
                                                   __bf16* __restrict__ Cl, int M,
                                                   int G,
                                                   const int* __restrict__ idx32,
                                                   const int* __restrict__ rank,
                                                   const int* __restrict__ offs,
                                                   int* __restrict__ csr, int E) {
    int bid = blockIdx.x;
    if (bid < G) {
        mfma_body<128>(A, Wthi, Wtlo, Cl, nullptr, M, bid);
        return;
    }
    bid -= G;
    int base = bid * 1024 + threadIdx.x;
    #pragma unroll
    for (int k = 0; k < 4; ++k) {
        int e = base + k * 256;
        if (e < E) {
            int d = idx32[E + e];
            csr[offs[d] + rank[e]] = idx32[e];
        }
    }
}

// layer-2 GEMM: A bf16 (exact) -> 2 MFMAs per step
__global__ __launch_bounds__(256) void k_mfma2(const __bf16* __restrict__ A,
                                               const __bf16* __restrict__ Wthi,
                                               const __bf16* __restrict__ Wtlo,
                                               __bf16* __restrict__ Cl,
                                               float* __restrict__ Cr, int M) {
    constexpr int K = 128;
    constexpr int SPLITC = 64;
    __shared__ __bf16 sB[2][128][40];
    const int tid = threadIdx.x;
    const int lane = tid & 63;
    const int wave = tid >> 6;
    const int row0 = blockIdx.x * 128 + wave * 32;
    const int rlo = lane & 15;
    const int rhi = lane >> 4;
    const int sc = tid >> 1;
    const int sseg = (tid & 1) * 16;

    f32x4 acc[4][2][2] = {};

    for (int k0 = 0; k0 < K; k0 += 32) {
        if (k0) __syncthreads();
        {
            const __bf16* gh = Wthi + (size_t)sc * K + k0 + sseg;
            const __bf16* gl = Wtlo + (size_t)sc * K + k0 + sseg;
            *(bf16x8*)(&sB[0][sc][sseg])     = *(const bf16x8*)gh;
            *(bf16x8*)(&sB[0][sc][sseg + 8]) = *(const bf16x8*)(gh + 8);
            *(bf16x8*)(&sB[1][sc][sseg])     = *(const bf16x8*)gl;
            *(bf16x8*)(&sB[1][sc][sseg + 8]) = *(const bf16x8*)(gl + 8);
        }
        bf16x8 a[2];
        #pragma unroll
        for (int wr = 0; wr < 2; ++wr) {
            int row = row0 + wr * 16 + rlo;
            row = row < M ? row : M - 1;
            a[wr] = *(const bf16x8*)(A + (size_t)row * K + k0 + rhi * 8);
        }
        __syncthreads();
        #pragma unroll
        for (int cs = 0; cs < 4; ++cs) {
            #pragma unroll
            for (int cf = 0; cf < 2; ++cf) {
                int c = cs * 32 + cf * 16 + rlo;
                bf16x8 bhi = *(const bf16x8*)(&sB[0][c][rhi * 8]);
                bf16x8 blo = *(const bf16x8*)(&sB[1][c][rhi * 8]);
                #pragma unroll
                for (int wr = 0; wr < 2; ++wr) {
                    f32x4 v = acc[cs][wr][cf];
                    v = __builtin_amdgcn_mfma_f32_16x16x32_bf16(a[wr], bhi, v, 0, 0, 0);
                    v = __builtin_amdgcn_mfma_f32_16x16x32_bf16(a[wr], blo, v, 0, 0, 0);
                    acc[cs][wr][cf] = v;
                }
            }
        }
    }

    #pragma unroll
    for (int cs = 0; cs < 4; ++cs)
        #pragma unroll
        for (int cf = 0; cf < 2; ++cf) {
            int c = cs * 32 + cf * 16 + rlo;
            #pragma unroll
            for (int wr = 0; wr < 2; ++wr)
                #pragma unroll
                for (int r = 0; r < 4; ++r) {
                    int row = row0 + wr * 16 + rhi * 4 + r;
                    if (row < M) {
                        float val = acc[cs][wr][cf][r];
                        if (c < SPLITC)
                            Cl[(size_t)row * SPLITC + c] = (__bf16)val;
                        else
                            Cr[(size_t)row * (128 - SPLITC) + (c - SPLITC)] = val;
                    }
                }
        }
}

// ---------------- fused gather(bf16) + mean + lin + BN(affine) + ReLU ------
// LINBF: lin is bf16 (layer 1) else f32 (layer 2)
template <int LOGF, bool LINBF>
__global__ __launch_bounds__(256) void k_agg(const __bf16* __restrict__ xl,
                                             const void* __restrict__ lin,
                                             const int* __restrict__ csr,
                                             const int* __restrict__ offs,
                                             const float* __restrict__ S,
                                             const float* __restrict__ T,
                                             void* __restrict__ out, int N) {
    constexpr int F = 1 << LOGF;
    constexpr int NW = (F == 128) ? 8 : 4;
    int node = blockIdx.x * 4 + (threadIdx.x >> 6);
    if (node >= N) return;
    int lane = threadIdx.x & 63;
    int sub = lane >> 4;
    int col = lane & 15;
    int beg = offs[node], end = offs[node + 1];
    float inv = 1.0f / fmaxf((float)(end - beg), 1.0f);

    float sx[NW];
    #pragma unroll
    for (int j = 0; j < NW; ++j) sx[j] = 0.f;

    int e = beg;
    while (e < end) {
        int bl = min(64, end - e);
        int myidx = (lane < bl) ? csr[e + lane] : 0;
        int u = 0;
        for (; u + 8 <= bl; u += 8) {
            int s0 = __shfl(myidx, u + sub, 64);
            int s1 = __shfl(myidx, u + 4 + sub, 64);
            if constexpr (F == 128) {
                uint4 t0 = *(const uint4*)((const char*)xl + (size_t)s0 * 256 + col * 16);
                uint4 t1 = *(const uint4*)((const char*)xl + (size_t)s1 * 256 + col * 16);
                unsigned int w0[4] = {t0.x, t0.y, t0.z, t0.w};
                unsigned int w1[4] = {t1.x, t1.y, t1.z, t1.w};
                #pragma unroll
                for (int i = 0; i < 4; ++i) {
                    sx[2 * i]     += __uint_as_float(w0[i] << 16) + __uint_as_float(w1[i] << 16);
                    sx[2 * i + 1] += __uint_as_float(w0[i] & 0xffff0000u) + __uint_as_float(w1[i] & 0xffff0000u);
                }
            } else {
                uint2 t0 = *(const uint2*)((const char*)xl + (size_t)s0 * 128 + col * 8);
                uint2 t1 = *(const uint2*)((const char*)xl + (size_t)s1 * 128 + col * 8);
                unsigned int w0[2] = {t0.x, t0.y};
                unsigned int w1[2] = {t1.x, t1.y};
                #pragma unroll
                for (int i = 0; i < 2; ++i) {
                    sx[2 * i]     += __uint_as_float(w0[i] << 16) + __uint_as_float(w1[i] << 16);
                    sx[2 * i + 1] += __uint_as_float(w0[i] & 0xffff0000u) + __uint_as_float(w1[i] & 0xffff0000u);
                }
            }
        }
        for (; u + 4 <= bl; u += 4) {
            int s0 = __shfl(myidx, u + sub, 64);
            if constexpr (F == 128) {
                uint4 t0 = *(const uint4*)((const char*)xl + (size_t)s0 * 256 + col * 16);
                unsigned int w0[4] = {t0.x, t0.y, t0.z, t0.w};
                #pragma unroll
                for (int i = 0; i < 4; ++i) {
                    sx[2 * i]     += __uint_as_float(w0[i] << 16);
                    sx[2 * i + 1] += __uint_as_float(w0[i] & 0xffff0000u);
                }
            } else {
                uint2 t0 = *(const uint2*)((const char*)xl + (size_t)s0 * 128 + col * 8);
                unsigned int w0[2] = {t0.x, t0.y};
                #pragma unroll
                for (int i = 0; i < 2; ++i) {
                    sx[2 * i]     += __uint_as_float(w0[i] << 16);
                    sx[2 * i + 1] += __uint_as_float(w0[i] & 0xffff0000u);
                }
            }
        }
        if (u < bl) {
            int rr = u + sub;
            int s0 = __shfl(myidx, rr < bl ? rr : u, 64);
            bool ok = rr < bl;
            if constexpr (F == 128) {
                uint4 t0 = *(const uint4*)((const char*)xl + (size_t)s0 * 256 + col * 16);
                unsigned int w0[4] = {t0.x, t0.y, t0.z, t0.w};
                #pragma unroll
                for (int i = 0; i < 4; ++i) {
                    sx[2 * i]     += ok ? __uint_as_float(w0[i] << 16) : 0.f;
                    sx[2 * i + 1] += ok ? __uint_as_float(w0[i] & 0xffff0000u) : 0.f;
                }
            } else {
                uint2 t0 = *(const uint2*)((const char*)xl + (size_t)s0 * 128 + col * 8);
                unsigned int w0[2] = {t0.x, t0.y};
                #pragma unroll
                for (int i = 0; i < 2; ++i) {
                    sx[2 * i]     += ok ? __uint_as_float(w0[i] << 16) : 0.f;
                    sx[2 * i + 1] += ok ? __uint_as_float(w0[i] & 0xffff0000u) : 0.f;
                }
            }
        }
        e += bl;
    }

    #pragma unroll
    for (int j = 0; j < NW; ++j) {
        sx[j] += __shfl_xor(sx[j], 16, 64);
        sx[j] += __shfl_xor(sx[j], 32, 64);
    }

    if (sub == 0) {
        if constexpr (F == 128) {
            float lv[8];
            if constexpr (LINBF) {
                uint4 l4 = *(const uint4*)((const char*)lin + ((size_t)node * 128 + col * 8) * 2);
                unsigned int lw[4] = {l4.x, l4.y, l4.z, l4.w};
                #pragma unroll
                for (int i = 0; i < 4; ++i) {
                    lv[2 * i]     = __uint_as_float(lw[i] << 16);
                    lv[2 * i + 1] = __uint_as_float(lw[i] & 0xffff0000u);
                }
            } else {
                const float4* lp = (const float4*)((const float*)lin + (size_t)node * 128 + col * 8);
                float4 l0 = lp[0], l1 = lp[1];
                lv[0] = l0.x; lv[1] = l0.y; lv[2] = l0.z; lv[3] = l0.w;
                lv[4] = l1.x; lv[5] = l1.y; lv[6] = l1.z; lv[7] = l1.w;
            }
            const float4* Sp = (const float4*)(S + col * 8);
            const float4* Tp = (const float4*)(T + col * 8);
            float4 Sa = Sp[0], Sb = Sp[1], Ta = Tp[0], Tb = Tp[1];
            float Sv[8] = {Sa.x, Sa.y, Sa.z, Sa.w, Sb.x, Sb.y, Sb.z, Sb.w};
            float Tv[8] = {Ta.x, Ta.y, Ta.z, Ta.w, Tb.x, Tb.y, Tb.z, Tb.w};
            unsigned int u[4];
            #pragma unroll
            for (int i = 0; i < 4; ++i) {
                float y0 = fmaxf(fmaf(fmaf(sx[2 * i], inv, lv[2 * i]), Sv[2 * i], Tv[2 * i]), 0.f);
                float y1 = fmaxf(fmaf(fmaf(sx[2 * i + 1], inv, lv[2 * i + 1]), Sv[2 * i + 1], Tv[2 * i + 1]), 0.f);
                u[i] = pk2(y0, y1);
            }
            *(uint4*)((char*)out + (size_t)node * 256 + col * 16) = make_uint4(u[0], u[1], u[2], u[3]);
        } else {
            float4 l = *(const float4*)((const float*)lin + (size_t)node * 64 + col * 4);
            float4 Sv = *(const float4*)(S + col * 4);
            float4 Tv = *(const float4*)(T + col * 4);
            float4 o;
            o.x = fmaxf(fmaf(fmaf(sx[0], inv, l.x), Sv.x, Tv.x), 0.f);
            o.y = fmaxf(fmaf(fmaf(sx[1], inv, l.y), Sv.y, Tv.y), 0.f);
            o.z = fmaxf(fmaf(fmaf(sx[2], inv, l.z), Sv.z, Tv.z), 0.f);
            o.w = fmaxf(fmaf(fmaf(sx[3], inv, l.w), Sv.w, Tv.w), 0.f);
            *(float4*)((float*)out + (size_t)node * 64 + col * 4) = o;
        }
    }
}

// ---------------- head ----------------
__global__ __launch_bounds__(256) void k_head(const float* __restrict__ h2,
                                              const float* __restrict__ Wh,
                                              const float* __restrict__ bh,
                                              float* __restrict__ out, int M) {
    __shared__ float sW[64 * 10];
    __shared__ float sb[10];
    for (int i = threadIdx.x; i < 640; i += 256) sW[i] = Wh[i];
    if (threadIdx.x < 10) sb[threadIdx.x] = bh[threadIdx.x];
    __syncthreads();
    int n = blockIdx.x * blockDim.x + threadIdx.x;
    if (n >= M) return;
    float acc[10];
    #pragma unroll
    for (int c = 0; c < 10; ++c) acc[c] = sb[c];
    const float* hr = h2 + (size_t)n * 64;
    #pragma unroll
    for (int k = 0; k < 64; ++k) {
        float hv = hr[k];
        #pragma unroll
        for (int c = 0; c < 10; ++c) acc[c] = fmaf(hv, sW[k * 10 + c], acc[c]);
    }
    #pragma unroll
    for (int c = 0; c < 10; ++c) out[(size_t)n * 10 + c] = acc[c];
}

// ---------------------------------------------------------------------------
static inline size_t align256(size_t x) { return (x + 255) & ~(size_t)255; }

extern "C" void kernel_launch(void* const* d_in, const int* in_sizes, int n_in,
                              void* d_out, int out_size, void* d_ws, size_t ws_size,
                              hipStream_t stream) {
    const float* x   = (const float*)d_in[0];
    const void*  ei  = d_in[1];
    const float* W1l = (const float*)d_in[2];
    const float* b1l = (const float*)d_in[3];
    const float* W1r = (const float*)d_in[4];
    const float* g1  = (const float*)d_in[5];
    const float* be1 = (const float*)d_in[6];
    const float* m1  = (const float*)d_in[7];
    const float* v1  = (const float*)d_in[8];
    const float* W2l = (const float*)d_in[9];
    const float* b2l = (const float*)d_in[10];
    const float* W2r = (const float*)d_in[11];
    const float* g2  = (const float*)d_in[12];
    const float* be2 = (const float*)d_in[13];
    const float* m2  = (const float*)d_in[14];
    const float* v2  = (const float*)d_in[15];
    const float* Wh  = (const float*)d_in[16];
    const float* bh  = (const float*)d_in[17];
    float* out = (float*)d_out;

    const int N = N_NODES;
    const int E = in_sizes[1] / 2;
    const int NB = (N + 255) / 256;

    // -------- workspace layout --------
    char* p = (char*)d_ws;
    int* idx32 = (int*)p;  p += align256((size_t)2 * E * 4);
    int* rank  = (int*)p;  p += align256((size_t)E * 4);
    int* csr   = (int*)p;  p += align256((size_t)E * 4);
    int* offs  = (int*)p;  p += align256((size_t)(N + 1) * 4);
    int* deg   = (int*)p;  p += align256((size_t)N * 64);      // 64 B / node
    int* bsum  = (int*)p;  p += 4096;
    float* bn  = (float*)p; p += 4096;   // S1[128] T1[128] S2[64] T2[64]
    __bf16* Wt1hi = (__bf16*)p; p += align256((size_t)256 * 128 * 2);
    __bf16* Wt1lo = (__bf16*)p; p += align256((size_t)256 * 128 * 2);
    __bf16* Wt2hi = (__bf16*)p; p += align256((size_t)128 * 128 * 2);
    __bf16* Wt2lo = (__bf16*)p; p += align256((size_t)128 * 128 * 2);
    __bf16* xl = (__bf16*)p; p += align256((size_t)N * 128 * 2);
    __bf16* xr = (__bf16*)p; p += align256((size_t)N * 128 * 2);  // bf16 lin (layer 1)
    __bf16* hb = (__bf16*)p; p += align256((size_t)N * 128 * 2);
    // layer-2 reuse
    __bf16* t2l = xl;                    // [N,64] bf16
    float* t2r  = (float*)xr;            // [N,64] f32 (25.6 MB fits)
    float* h2   = (float*)hb;            // [N,64] f32

    dim3 blk(256);
    const int WPB = (2 * 128 * 128 + 2 * 64 * 128 + 255) / 256;   // 192
    int prepB = (E + 255) / 256;
    int G = (N + 127) / 128;
    int binBlocks = (E + 1023) / 1024;

    // -------- K0: weight/BN prep + deg zero --------
    hipMemsetAsync(deg, 0, (size_t)N * 64, stream);
    k_wbn<<<dim3(WPB + 1), blk, 0, stream>>>(WPB,
        W1l, W1r, W2l, W2r, Wt1hi, Wt1lo, Wt2hi, Wt2lo,
        b1l, g1, be1, m1, v1, b2l, g2, be2, m2, v2, bn);

    // -------- K1: edge prep (padded-deg atomics) || GEMM half1 -> xl -------
    k_prep_gemm<<<dim3(prepB + G), blk, 0, stream>>>(
        (const unsigned int*)ei, E, idx32, rank, deg, prepB,
        x, Wt1hi, Wt1lo, xl, N);

    // -------- scans --------
    k_scan1<<<dim3(NB), blk, 0, stream>>>(deg, offs, bsum, N);
    k_scan2<<<dim3(1), blk, 0, stream>>>(bsum, NB);
    k_scan3<<<dim3(NB), blk, 0, stream>>>(offs, bsum, N, E);

    // -------- K3: GEMM half2 -> xr (bf16) || CSR scatter --------
    k_gemm_scat<<<dim3(G + binBlocks), blk, 0, stream>>>(
        x, Wt1hi + 128 * 128, Wt1lo + 128 * 128, xr, N, G,
        idx32, rank, offs, csr, E);

    // -------- layer 1 aggregate (bf16 lin, bf16 out) --------
    k_agg<7, true><<<dim3((N + 3) / 4), blk, 0, stream>>>(
        xl, xr, csr, offs, bn, bn + 128, hb, N);

    // -------- layer 2 --------
    k_mfma2<<<dim3(G), blk, 0, stream>>>(hb, Wt2hi, Wt2lo, t2l, t2r, N);
    k_agg<6, false><<<dim3((N + 3) / 4), blk, 0, stream>>>(
        t2l, t2r, csr, offs, bn + 256, bn + 320, h2, N);

    // -------- head --------
    k_head<<<dim3((N + 255) / 256), blk, 0, stream>>>(h2, Wh, bh, out, N);
}

// Round 13
// 297.708 us; speedup vs baseline: 1.0143x; 1.0143x over previous
//
#include <hip/hip_runtime.h>
#include <hip/hip_bf16.h>
#include <stdint.h>

#define N_NODES 100000
constexpr float BN_EPS = 1e-5f;

typedef __bf16 bf16x8 __attribute__((ext_vector_type(8)));
typedef float f32x4 __attribute__((ext_vector_type(4)));

__device__ inline unsigned int pk2(float a, float b) {
    __bf16 x = (__bf16)a, y = (__bf16)b;
    return (unsigned int)__builtin_bit_cast(unsigned short, x) |
           ((unsigned int)__builtin_bit_cast(unsigned short, y) << 16);
}

// ---------------- fused weight-prep + BN-prep + edge prep (low VGPR) -------
// deg padded: 16 ints (64 B) per node -> no inter-node cache-line contention
__global__ __launch_bounds__(256) void k_prep(const unsigned int* __restrict__ w, int E,
                                              int* __restrict__ idx32,
                                              int* __restrict__ rank,
                                              int* __restrict__ deg, int wpB,
                                              const float* __restrict__ W1l,
                                              const float* __restrict__ W1r,
                                              const float* __restrict__ W2l,
                                              const float* __restrict__ W2r,
                                              __bf16* __restrict__ Wt1hi,
                                              __bf16* __restrict__ Wt1lo,
                                              __bf16* __restrict__ Wt2hi,
                                              __bf16* __restrict__ Wt2lo,
                                              const float* __restrict__ b1l,
                                              const float* __restrict__ g1,
                                              const float* __restrict__ be1,
                                              const float* __restrict__ m1,
                                              const float* __restrict__ v1,
                                              const float* __restrict__ b2l,
                                              const float* __restrict__ g2,
                                              const float* __restrict__ be2,
                                              const float* __restrict__ m2,
                                              const float* __restrict__ v2,
                                              float* __restrict__ bn) {
    if ((int)blockIdx.x < wpB) {
        int idx = blockIdx.x * 256 + threadIdx.x;
        const float* W; __bf16 *Whi, *Wlo; int halfN, lidx;
        if (idx < 2 * 128 * 128) {
            lidx = idx; halfN = 128; Whi = Wt1hi; Wlo = Wt1lo;
            W = ((lidx >> 7) < 128) ? W1l : W1r;
        } else {
            lidx = idx - 2 * 128 * 128;
            if (lidx >= 2 * 64 * 128) return;
            halfN = 64; Whi = Wt2hi; Wlo = Wt2lo;
            W = ((lidx >> 7) < 64) ? W2l : W2r;
        }
        int c = lidx >> 7, k = lidx & 127;
        int cc = (c < halfN) ? c : c - halfN;
        float v = W[(size_t)k * halfN + cc];
        __bf16 h = (__bf16)v;
        Whi[lidx] = h;
        Wlo[lidx] = (__bf16)(v - (float)h);
        return;
    }
    if ((int)blockIdx.x == wpB) {
        int t = threadIdx.x;
        if (t < 128) {
            float S = g1[t] * rsqrtf(v1[t] + BN_EPS);
            bn[t] = S;
            bn[128 + t] = (b1l[t] - m1[t]) * S + be1[t];
        } else if (t < 192) {
            int f = t - 128;
            float S = g2[f] * rsqrtf(v2[f] + BN_EPS);
            bn[256 + f] = S;
            bn[320 + f] = (b2l[f] - m2[f]) * S + be2[f];
        }
        return;
    }
    // int64 detection: odd words of first 64 edges are high halves (always 0
    // for int64 since idx<1e5); random src indices for int32.
    unsigned int wv = w[1 + 2 * (threadIdx.x & 63)];
    int f = __any(wv != 0);            // 1 => int32, 0 => int64
    int e = (blockIdx.x - wpB - 1) * 256 + threadIdx.x;
    if (e >= E) return;
    int s = (int)(f ? w[e] : w[2 * (size_t)e]);
    int d = (int)(f ? w[E + e] : w[2 * ((size_t)E + e)]);
    idx32[e] = s;
    idx32[E + e] = d;
    rank[e] = atomicAdd(&deg[d << 4], 1);
}

// ---------------- scans (deg strided by 16) ----------------
__global__ __launch_bounds__(256) void k_scan1(const int* __restrict__ deg,
                                               int* __restrict__ offs,
                                               int* __restrict__ bsum, int n) {
    __shared__ int s[256];
    int t = threadIdx.x;
    int i = blockIdx.x * 256 + t;
    int v = (i < n) ? deg[i << 4] : 0;
    s[t] = v;
    __syncthreads();
    for (int off = 1; off < 256; off <<= 1) {
        int add = (t >= off) ? s[t - off] : 0;
        __syncthreads();
        s[t] += add;
        __syncthreads();
    }
    if (i < n) offs[i] = s[t] - v;
    if (t == 255) bsum[blockIdx.x] = s[255];
}

__global__ __launch_bounds__(256) void k_scan2(int* __restrict__ bsum, int nb) {
    __shared__ int s[256];
    __shared__ int carry;
    int t = threadIdx.x;
    if (t == 0) carry = 0;
    __syncthreads();
    for (int base = 0; base < nb; base += 256) {
        int i = base + t;
        int v = (i < nb) ? bsum[i] : 0;
        s[t] = v;
        __syncthreads();
        for (int off = 1; off < 256; off <<= 1) {
            int add = (t >= off) ? s[t - off] : 0;
            __syncthreads();
            s[t] += add;
            __syncthreads();
        }
        if (i < nb) bsum[i] = s[t] - v + carry;
        __syncthreads();
        if (t == 0) carry += s[255];
        __syncthreads();
    }
}

__global__ void k_scan3(int* __restrict__ offs, const int* __restrict__ bsum,
                        int n, int E) {
    int i = blockIdx.x * blockDim.x + threadIdx.x;
    if (i < n) offs[i] += bsum[i >> 8];
    if (i == 0) offs[n] = E;
}

// ---------------- bf16x3 MFMA GEMM body (f32 A), B staged in LDS ----------
// All 128 out cols -> Cl (bf16)
__device__ void mfma_body(const float* __restrict__ A,
                          const __bf16* __restrict__ Wthi,
                          const __bf16* __restrict__ Wtlo,
                          __bf16* __restrict__ Cl, int M, int bid) {
    constexpr int K = 128;
    __shared__ __bf16 sB[2][128][40];     // 20 KB
    const int tid = threadIdx.x;
    const int lane = tid & 63;
    const int wave = tid >> 6;
    const int row0 = bid * 128 + wave * 32;
    const int rlo = lane & 15;
    const int rhi = lane >> 4;

    const int sc = tid >> 1;
    const int sseg = (tid & 1) * 16;

    f32x4 acc[4][2][2] = {};

    for (int k0 = 0; k0 < K; k0 += 32) {
        if (k0) __syncthreads();
        {
            const __bf16* gh = Wthi + (size_t)sc * K + k0 + sseg;
            const __bf16* gl = Wtlo + (size_t)sc * K + k0 + sseg;
            *(bf16x8*)(&sB[0][sc][sseg])     = *(const bf16x8*)gh;
            *(bf16x8*)(&sB[0][sc][sseg + 8]) = *(const bf16x8*)(gh + 8);
            *(bf16x8*)(&sB[1][sc][sseg])     = *(const bf16x8*)gl;
            *(bf16x8*)(&sB[1][sc][sseg + 8]) = *(const bf16x8*)(gl + 8);
        }
        bf16x8 ahi[2], alo[2];
        #pragma unroll
        for (int wr = 0; wr < 2; ++wr) {
            int row = row0 + wr * 16 + rlo;
            row = row < M ? row : M - 1;
            const float* ap = A + (size_t)row * K + k0 + rhi * 8;
            float4 v0 = *(const float4*)ap;
            float4 v1 = *(const float4*)(ap + 4);
            float vv[8] = {v0.x, v0.y, v0.z, v0.w, v1.x, v1.y, v1.z, v1.w};
            #pragma unroll
            for (int i = 0; i < 8; ++i) {
                __bf16 h = (__bf16)vv[i];
                ahi[wr][i] = h;
                alo[wr][i] = (__bf16)(vv[i] - (float)h);
            }
        }
        __syncthreads();
        #pragma unroll
        for (int cs = 0; cs < 4; ++cs) {
            #pragma unroll
            for (int cf = 0; cf < 2; ++cf) {
                int c = cs * 32 + cf * 16 + rlo;
                bf16x8 bhi = *(const bf16x8*)(&sB[0][c][rhi * 8]);
                bf16x8 blo = *(const bf16x8*)(&sB[1][c][rhi * 8]);
                #pragma unroll
                for (int wr = 0; wr < 2; ++wr) {
                    f32x4 a = acc[cs][wr][cf];
                    a = __builtin_amdgcn_mfma_f32_16x16x32_bf16(ahi[wr], bhi, a, 0, 0, 0);
                    a = __builtin_amdgcn_mfma_f32_16x16x32_bf16(ahi[wr], blo, a, 0, 0, 0);
                    a = __builtin_amdgcn_mfma_f32_16x16x32_bf16(alo[wr], bhi, a, 0, 0, 0);
                    acc[cs][wr][cf] = a;
                }
            }
        }
    }

    #pragma unroll
    for (int cs = 0; cs < 4; ++cs)
        #pragma unroll
        for (int cf = 0; cf < 2; ++cf) {
            int c = cs * 32 + cf * 16 + rlo;
            #pragma unroll
            for (int wr = 0; wr < 2; ++wr)
                #pragma unroll
                for (int r = 0; r < 4; ++r) {
                    int row = row0 + wr * 16 + rhi * 4 + r;
                    if (row < M)
                        Cl[(size_t)row * 128 + c] = (__bf16)acc[cs][wr][cf][r];
                }
        }
}

// fused layer-1 GEMM (two 128-col halves -> xl, xr both bf16) + CSR scatter
__global__ __launch_bounds__(256) void k_mfma_bin(const float* __restrict__ A,
                                                  const __bf16* __restrict__ Wthi,
                                                  const __bf16* __restrict__ Wtlo,
                                                  __bf16* __restrict__ Cl,
                                                  __bf16* __restrict__ Cr, int M,
                                                  int G,
                                                  const int* __restrict__ idx32,
                                                  const int* __restrict__ rank,
                                                  const int* __restrict__ offs,
                                                  int* __restrict__ csr, int E) {
    int bid = blockIdx.x;
    if (bid < G) {
        mfma_body(A, Wthi, Wtlo, Cl, M, bid);
        return;
    }
    bid -= G;
    if (bid < G) {
        mfma_body(A, Wthi + 128 * 128, Wtlo + 128 * 128, Cr, M, bid);
        return;
    }
    bid -= G;
    int base = bid * 1024 + threadIdx.x;
    #pragma unroll
    for (int k = 0; k < 4; ++k) {
        int e = base + k * 256;
        if (e < E) {
            int d = idx32[E + e];
            csr[offs[d] + rank[e]] = idx32[e];
        }
    }
}

// layer-2 GEMM: A bf16 (exact) -> 2 MFMAs per step; cols 0-63 bf16, 64-127 f32
__global__ __launch_bounds__(256) void k_mfma2(const __bf16* __restrict__ A,
                                               const __bf16* __restrict__ Wthi,
                                               const __bf16* __restrict__ Wtlo,
                                               __bf16* __restrict__ Cl,
                                               float* __restrict__ Cr, int M) {
    constexpr int K = 128;
    constexpr int SPLITC = 64;
    __shared__ __bf16 sB[2][128][40];
    const int tid = threadIdx.x;
    const int lane = tid & 63;
    const int wave = tid >> 6;
    const int row0 = blockIdx.x * 128 + wave * 32;
    const int rlo = lane & 15;
    const int rhi = lane >> 4;
    const int sc = tid >> 1;
    const int sseg = (tid & 1) * 16;

    f32x4 acc[4][2][2] = {};

    for (int k0 = 0; k0 < K; k0 += 32) {
        if (k0) __syncthreads();
        {
            const __bf16* gh = Wthi + (size_t)sc * K + k0 + sseg;
            const __bf16* gl = Wtlo + (size_t)sc * K + k0 + sseg;
            *(bf16x8*)(&sB[0][sc][sseg])     = *(const bf16x8*)gh;
            *(bf16x8*)(&sB[0][sc][sseg + 8]) = *(const bf16x8*)(gh + 8);
            *(bf16x8*)(&sB[1][sc][sseg])     = *(const bf16x8*)gl;
            *(bf16x8*)(&sB[1][sc][sseg + 8]) = *(const bf16x8*)(gl + 8);
        }
        bf16x8 a[2];
        #pragma unroll
        for (int wr = 0; wr < 2; ++wr) {
            int row = row0 + wr * 16 + rlo;
            row = row < M ? row : M - 1;
            a[wr] = *(const bf16x8*)(A + (size_t)row * K + k0 + rhi * 8);
        }
        __syncthreads();
        #pragma unroll
        for (int cs = 0; cs < 4; ++cs) {
            #pragma unroll
            for (int cf = 0; cf < 2; ++cf) {
                int c = cs * 32 + cf * 16 + rlo;
                bf16x8 bhi = *(const bf16x8*)(&sB[0][c][rhi * 8]);
                bf16x8 blo = *(const bf16x8*)(&sB[1][c][rhi * 8]);
                #pragma unroll
                for (int wr = 0; wr < 2; ++wr) {
                    f32x4 v = acc[cs][wr][cf];
                    v = __builtin_amdgcn_mfma_f32_16x16x32_bf16(a[wr], bhi, v, 0, 0, 0);
                    v = __builtin_amdgcn_mfma_f32_16x16x32_bf16(a[wr], blo, v, 0, 0, 0);
                    acc[cs][wr][cf] = v;
                }
            }
        }
    }

    #pragma unroll
    for (int cs = 0; cs < 4; ++cs)
        #pragma unroll
        for (int cf = 0; cf < 2; ++cf) {
            int c = cs * 32 + cf * 16 + rlo;
            #pragma unroll
            for (int wr = 0; wr < 2; ++wr)
                #pragma unroll
                for (int r = 0; r < 4; ++r) {
                    int row = row0 + wr * 16 + rhi * 4 + r;
                    if (row < M) {
                        float val = acc[cs][wr][cf][r];
                        if (c < SPLITC)
                            Cl[(size_t)row * SPLITC + c] = (__bf16)val;
                        else
                            Cr[(size_t)row * (128 - SPLITC) + (c - SPLITC)] = val;
                    }
                }
        }
}

// ---------------- fused gather(bf16) + mean + lin + BN(affine) + ReLU ------
// LINBF: lin is bf16 (layer 1) else f32 (layer 2)
template <int LOGF, bool LINBF>
__global__ __launch_bounds__(256) void k_agg(const __bf16* __restrict__ xl,
                                             const void* __restrict__ lin,
                                             const int* __restrict__ csr,
                                             const int* __restrict__ offs,
                                             const float* __restrict__ S,
                                             const float* __restrict__ T,
                                             void* __restrict__ out, int N) {
    constexpr int F = 1 << LOGF;
    constexpr int NW = (F == 128) ? 8 : 4;
    int node = blockIdx.x * 4 + (threadIdx.x >> 6);
    if (node >= N) return;
    int lane = threadIdx.x & 63;
    int sub = lane >> 4;
    int col = lane & 15;
    int beg = offs[node], end = offs[node + 1];
    float inv = 1.0f / fmaxf((float)(end - beg), 1.0f);

    float sx[NW];
    #pragma unroll
    for (int j = 0; j < NW; ++j) sx[j] = 0.f;

    int e = beg;
    while (e < end) {
        int bl = min(64, end - e);
        int myidx = (lane < bl) ? csr[e + lane] : 0;
        int u = 0;
        for (; u + 8 <= bl; u += 8) {
            int s0 = __shfl(myidx, u + sub, 64);
            int s1 = __shfl(myidx, u + 4 + sub, 64);
            if constexpr (F == 128) {
                uint4 t0 = *(const uint4*)((const char*)xl + (size_t)s0 * 256 + col * 16);
                uint4 t1 = *(const uint4*)((const char*)xl + (size_t)s1 * 256 + col * 16);
                unsigned int w0[4] = {t0.x, t0.y, t0.z, t0.w};
                unsigned int w1[4] = {t1.x, t1.y, t1.z, t1.w};
                #pragma unroll
                for (int i = 0; i < 4; ++i) {
                    sx[2 * i]     += __uint_as_float(w0[i] << 16) + __uint_as_float(w1[i] << 16);
                    sx[2 * i + 1] += __uint_as_float(w0[i] & 0xffff0000u) + __uint_as_float(w1[i] & 0xffff0000u);
                }
            } else {
                uint2 t0 = *(const uint2*)((const char*)xl + (size_t)s0 * 128 + col * 8);
                uint2 t1 = *(const uint2*)((const char*)xl + (size_t)s1 * 128 + col * 8);
                unsigned int w0[2] = {t0.x, t0.y};
                unsigned int w1[2] = {t1.x, t1.y};
                #pragma unroll
                for (int i = 0; i < 2; ++i) {
                    sx[2 * i]     += __uint_as_float(w0[i] << 16) + __uint_as_float(w1[i] << 16);
                    sx[2 * i + 1] += __uint_as_float(w0[i] & 0xffff0000u) + __uint_as_float(w1[i] & 0xffff0000u);
                }
            }
        }
        for (; u + 4 <= bl; u += 4) {
            int s0 = __shfl(myidx, u + sub, 64);
            if constexpr (F == 128) {
                uint4 t0 = *(const uint4*)((const char*)xl + (size_t)s0 * 256 + col * 16);
                unsigned int w0[4] = {t0.x, t0.y, t0.z, t0.w};
                #pragma unroll
                for (int i = 0; i < 4; ++i) {
                    sx[2 * i]     += __uint_as_float(w0[i] << 16);
                    sx[2 * i + 1] += __uint_as_float(w0[i] & 0xffff0000u);
                }
            } else {
                uint2 t0 = *(const uint2*)((const char*)xl + (size_t)s0 * 128 + col * 8);
                unsigned int w0[2] = {t0.x, t0.y};
                #pragma unroll
                for (int i = 0; i < 2; ++i) {
                    sx[2 * i]     += __uint_as_float(w0[i] << 16);
                    sx[2 * i + 1] += __uint_as_float(w0[i] & 0xffff0000u);
                }
            }
        }
        if (u < bl) {
            int rr = u + sub;
            int s0 = __shfl(myidx, rr < bl ? rr : u, 64);
            bool ok = rr < bl;
            if constexpr (F == 128) {
                uint4 t0 = *(const uint4*)((const char*)xl + (size_t)s0 * 256 + col * 16);
                unsigned int w0[4] = {t0.x, t0.y, t0.z, t0.w};
                #pragma unroll
                for (int i = 0; i < 4; ++i) {
                    sx[2 * i]     += ok ? __uint_as_float(w0[i] << 16) : 0.f;
                    sx[2 * i + 1] += ok ? __uint_as_float(w0[i] & 0xffff0000u) : 0.f;
                }
            } else {
                uint2 t0 = *(const uint2*)((const char*)xl + (size_t)s0 * 128 + col * 8);
                unsigned int w0[2] = {t0.x, t0.y};
                #pragma unroll
                for (int i = 0; i < 2; ++i) {
                    sx[2 * i]     += ok ? __uint_as_float(w0[i] << 16) : 0.f;
                    sx[2 * i + 1] += ok ? __uint_as_float(w0[i] & 0xffff0000u) : 0.f;
                }
            }
        }
        e += bl;
    }

    #pragma unroll
    for (int j = 0; j < NW; ++j) {
        sx[j] += __shfl_xor(sx[j], 16, 64);
        sx[j] += __shfl_xor(sx[j], 32, 64);
    }

    if (sub == 0) {
        if constexpr (F == 128) {
            float lv[8];
            if constexpr (LINBF) {
                uint4 l4 = *(const uint4*)((const char*)lin + ((size_t)node * 128 + col * 8) * 2);
                unsigned int lw[4] = {l4.x, l4.y, l4.z, l4.w};
                #pragma unroll
                for (int i = 0; i < 4; ++i) {
                    lv[2 * i]     = __uint_as_float(lw[i] << 16);
                    lv[2 * i + 1] = __uint_as_float(lw[i] & 0xffff0000u);
                }
            } else {
                const float4* lp = (const float4*)((const float*)lin + (size_t)node * 128 + col * 8);
                float4 l0 = lp[0], l1 = lp[1];
                lv[0] = l0.x; lv[1] = l0.y; lv[2] = l0.z; lv[3] = l0.w;
                lv[4] = l1.x; lv[5] = l1.y; lv[6] = l1.z; lv[7] = l1.w;
            }
            const float4* Sp = (const float4*)(S + col * 8);
            const float4* Tp = (const float4*)(T + col * 8);
            float4 Sa = Sp[0], Sb = Sp[1], Ta = Tp[0], Tb = Tp[1];
            float Sv[8] = {Sa.x, Sa.y, Sa.z, Sa.w, Sb.x, Sb.y, Sb.z, Sb.w};
            float Tv[8] = {Ta.x, Ta.y, Ta.z, Ta.w, Tb.x, Tb.y, Tb.z, Tb.w};
            unsigned int u[4];
            #pragma unroll
            for (int i = 0; i < 4; ++i) {
                float y0 = fmaxf(fmaf(fmaf(sx[2 * i], inv, lv[2 * i]), Sv[2 * i], Tv[2 * i]), 0.f);
                float y1 = fmaxf(fmaf(fmaf(sx[2 * i + 1], inv, lv[2 * i + 1]), Sv[2 * i + 1], Tv[2 * i + 1]), 0.f);
                u[i] = pk2(y0, y1);
            }
            *(uint4*)((char*)out + (size_t)node * 256 + col * 16) = make_uint4(u[0], u[1], u[2], u[3]);
        } else {
            float4 l = *(const float4*)((const float*)lin + (size_t)node * 64 + col * 4);
            float4 Sv = *(const float4*)(S + col * 4);
            float4 Tv = *(const float4*)(T + col * 4);
            float4 o;
            o.x = fmaxf(fmaf(fmaf(sx[0], inv, l.x), Sv.x, Tv.x), 0.f);
            o.y = fmaxf(fmaf(fmaf(sx[1], inv, l.y), Sv.y, Tv.y), 0.f);
            o.z = fmaxf(fmaf(fmaf(sx[2], inv, l.z), Sv.z, Tv.z), 0.f);
            o.w = fmaxf(fmaf(fmaf(sx[3], inv, l.w), Sv.w, Tv.w), 0.f);
            *(float4*)((float*)out + (size_t)node * 64 + col * 4) = o;
        }
    }
}

// ---------------- head ----------------
__global__ __launch_bounds__(256) void k_head(const float* __restrict__ h2,
                                              const float* __restrict__ Wh,
                                              const float* __restrict__ bh,
                                              float* __restrict__ out, int M) {
    __shared__ float sW[64 * 10];
    __shared__ float sb[10];
    for (int i = threadIdx.x; i < 640; i += 256) sW[i] = Wh[i];
    if (threadIdx.x < 10) sb[threadIdx.x] = bh[threadIdx.x];
    __syncthreads();
    int n = blockIdx.x * blockDim.x + threadIdx.x;
    if (n >= M) return;
    float acc[10];
    #pragma unroll
    for (int c = 0; c < 10; ++c) acc[c] = sb[c];
    const float* hr = h2 + (size_t)n * 64;
    #pragma unroll
    for (int k = 0; k < 64; ++k) {
        float hv = hr[k];
        #pragma unroll
        for (int c = 0; c < 10; ++c) acc[c] = fmaf(hv, sW[k * 10 + c], acc[c]);
    }
    #pragma unroll
    for (int c = 0; c < 10; ++c) out[(size_t)n * 10 + c] = acc[c];
}

// ---------------------------------------------------------------------------
static inline size_t align256(size_t x) { return (x + 255) & ~(size_t)255; }

extern "C" void kernel_launch(void* const* d_in, const int* in_sizes, int n_in,
                              void* d_out, int out_size, void* d_ws, size_t ws_size,
                              hipStream_t stream) {
    const float* x   = (const float*)d_in[0];
    const void*  ei  = d_in[1];
    const float* W1l = (const float*)d_in[2];
    const float* b1l = (const float*)d_in[3];
    const float* W1r = (const float*)d_in[4];
    const float* g1  = (const float*)d_in[5];
    const float* be1 = (const float*)d_in[6];
    const float* m1  = (const float*)d_in[7];
    const float* v1  = (const float*)d_in[8];
    const float* W2l = (const float*)d_in[9];
    const float* b2l = (const float*)d_in[10];
    const float* W2r = (const float*)d_in[11];
    const float* g2  = (const float*)d_in[12];
    const float* be2 = (const float*)d_in[13];
    const float* m2  = (const float*)d_in[14];
    const float* v2  = (const float*)d_in[15];
    const float* Wh  = (const float*)d_in[16];
    const float* bh  = (const float*)d_in[17];
    float* out = (float*)d_out;

    const int N = N_NODES;
    const int E = in_sizes[1] / 2;
    const int NB = (N + 255) / 256;

    // -------- workspace layout --------
    char* p = (char*)d_ws;
    int* idx32 = (int*)p;  p += align256((size_t)2 * E * 4);
    int* rank  = (int*)p;  p += align256((size_t)E * 4);
    int* csr   = (int*)p;  p += align256((size_t)E * 4);
    int* offs  = (int*)p;  p += align256((size_t)(N + 1) * 4);
    int* deg   = (int*)p;  p += align256((size_t)N * 64);      // 64 B / node
    int* bsum  = (int*)p;  p += 4096;
    float* bn  = (float*)p; p += 4096;   // S1[128] T1[128] S2[64] T2[64]
    __bf16* Wt1hi = (__bf16*)p; p += align256((size_t)256 * 128 * 2);
    __bf16* Wt1lo = (__bf16*)p; p += align256((size_t)256 * 128 * 2);
    __bf16* Wt2hi = (__bf16*)p; p += align256((size_t)128 * 128 * 2);
    __bf16* Wt2lo = (__bf16*)p; p += align256((size_t)128 * 128 * 2);
    __bf16* xl = (__bf16*)p; p += align256((size_t)N * 128 * 2);
    __bf16* xr = (__bf16*)p; p += align256((size_t)N * 128 * 2);
    __bf16* hb = (__bf16*)p; p += align256((size_t)N * 128 * 2);
    // layer-2 reuse
    __bf16* t2l = xl;                    // [N,64] bf16
    float* t2r  = (float*)xr;            // [N,64] f32
    float* h2   = (float*)hb;            // [N,64] f32

    dim3 blk(256);
    const int WPB = (2 * 128 * 128 + 2 * 64 * 128 + 255) / 256;   // 192
    int prepB = (E + 255) / 256;
    int G = (N + 127) / 128;
    int binBlocks = (E + 1023) / 1024;

    // -------- fused weight/BN/edge prep (low VGPR, padded deg) --------
    hipMemsetAsync(deg, 0, (size_t)N * 64, stream);
    k_prep<<<dim3(WPB + 1 + prepB), blk, 0, stream>>>(
        (const unsigned int*)ei, E, idx32, rank, deg, WPB,
        W1l, W1r, W2l, W2r, Wt1hi, Wt1lo, Wt2hi, Wt2lo,
        b1l, g1, be1, m1, v1, b2l, g2, be2, m2, v2, bn);

    // -------- scans --------
    k_scan1<<<dim3(NB), blk, 0, stream>>>(deg, offs, bsum, N);
    k_scan2<<<dim3(1), blk, 0, stream>>>(bsum, NB);
    k_scan3<<<dim3(NB), blk, 0, stream>>>(offs, bsum, N, E);

    // -------- layer-1 GEMM (two halves -> bf16 xl, xr) + CSR scatter ------
    k_mfma_bin<<<dim3(2 * G + binBlocks), blk, 0, stream>>>(
        x, Wt1hi, Wt1lo, xl, xr, N, G, idx32, rank, offs, csr, E);

    // -------- layer 1 aggregate (bf16 lin, bf16 out) --------
    k_agg<7, true><<<dim3((N + 3) / 4), blk, 0, stream>>>(
        xl, xr, csr, offs, bn, bn + 128, hb, N);

    // -------- layer 2 --------
    k_mfma2<<<dim3(G), blk, 0, stream>>>(hb, Wt2hi, Wt2lo, t2l, t2r, N);
    k_agg<6, false><<<dim3((N + 3) / 4), blk, 0, stream>>>(
        t2l, t2r, csr, offs, bn + 256, bn + 320, h2, N);

    // -------- head --------
    k_head<<<dim3((N + 255) / 256), blk, 0, stream>>>(h2, Wh, bh, out, N);
}

// Round 14
// 282.610 us; speedup vs baseline: 1.0685x; 1.0534x over previous
//
#include <hip/hip_runtime.h>
#include <hip/hip_bf16.h>
#include <stdint.h>

#define N_NODES 100000
constexpr float BN_EPS = 1e-5f;

typedef __bf16 bf16x8 __attribute__((ext_vector_type(8)));
typedef float f32x4 __attribute__((ext_vector_type(4)));

__device__ inline unsigned int pk2(float a, float b) {
    __bf16 x = (__bf16)a, y = (__bf16)b;
    return (unsigned int)__builtin_bit_cast(unsigned short, x) |
           ((unsigned int)__builtin_bit_cast(unsigned short, y) << 16);
}

// ---------------- fused weight-prep + BN-prep + edge prep ----------------
// deg padded: 16 ints (64 B) per node -> no inter-node cache-line contention
__global__ __launch_bounds__(256) void k_prep(const unsigned int* __restrict__ w, int E,
                                              int* __restrict__ idx32,
                                              int* __restrict__ rank,
                                              int* __restrict__ deg, int wpB,
                                              const float* __restrict__ W1l,
                                              const float* __restrict__ W1r,
                                              const float* __restrict__ W2l,
                                              const float* __restrict__ W2r,
                                              __bf16* __restrict__ Wt1hi,
                                              __bf16* __restrict__ Wt1lo,
                                              __bf16* __restrict__ Wt2hi,
                                              __bf16* __restrict__ Wt2lo,
                                              const float* __restrict__ b1l,
                                              const float* __restrict__ g1,
                                              const float* __restrict__ be1,
                                              const float* __restrict__ m1,
                                              const float* __restrict__ v1,
                                              const float* __restrict__ b2l,
                                              const float* __restrict__ g2,
                                              const float* __restrict__ be2,
                                              const float* __restrict__ m2,
                                              const float* __restrict__ v2,
                                              float* __restrict__ bn) {
    if ((int)blockIdx.x < wpB) {
        int idx = blockIdx.x * 256 + threadIdx.x;
        const float* W; __bf16 *Whi, *Wlo; int halfN, lidx;
        if (idx < 2 * 128 * 128) {
            lidx = idx; halfN = 128; Whi = Wt1hi; Wlo = Wt1lo;
            W = ((lidx >> 7) < 128) ? W1l : W1r;
        } else {
            lidx = idx - 2 * 128 * 128;
            if (lidx >= 2 * 64 * 128) return;
            halfN = 64; Whi = Wt2hi; Wlo = Wt2lo;
            W = ((lidx >> 7) < 64) ? W2l : W2r;
        }
        int c = lidx >> 7, k = lidx & 127;
        int cc = (c < halfN) ? c : c - halfN;
        float v = W[(size_t)k * halfN + cc];
        __bf16 h = (__bf16)v;
        Whi[lidx] = h;
        Wlo[lidx] = (__bf16)(v - (float)h);
        return;
    }
    if ((int)blockIdx.x == wpB) {
        int t = threadIdx.x;
        if (t < 128) {                                   // layer-1 S/T
            float S = g1[t] * rsqrtf(v1[t] + BN_EPS);
            bn[t] = S;
            bn[128 + t] = (b1l[t] - m1[t]) * S + be1[t];
        } else if (t < 192) {                            // layer-2 S/T
            int f = t - 128;
            float S = g2[f] * rsqrtf(v2[f] + BN_EPS);
            bn[256 + f] = S;
            bn[320 + f] = (b2l[f] - m2[f]) * S + be2[f];
        }
        return;
    }
    // int64 detection: odd words of first 64 edges are high halves (always 0
    // for int64 since idx<1e5); random src indices for int32.
    unsigned int wv = w[1 + 2 * (threadIdx.x & 63)];
    int f = __any(wv != 0);            // 1 => int32, 0 => int64
    int e = (blockIdx.x - wpB - 1) * 256 + threadIdx.x;
    if (e >= E) return;
    int s = (int)(f ? w[e] : w[2 * (size_t)e]);
    int d = (int)(f ? w[E + e] : w[2 * ((size_t)E + e)]);
    idx32[e] = s;
    idx32[E + e] = d;
    rank[e] = atomicAdd(&deg[d << 4], 1);
}

// ---------------- scans (deg strided by 16) ----------------
__global__ __launch_bounds__(256) void k_scan1(const int* __restrict__ deg,
                                               int* __restrict__ offs,
                                               int* __restrict__ bsum, int n) {
    __shared__ int s[256];
    int t = threadIdx.x;
    int i = blockIdx.x * 256 + t;
    int v = (i < n) ? deg[i << 4] : 0;
    s[t] = v;
    __syncthreads();
    for (int off = 1; off < 256; off <<= 1) {
        int add = (t >= off) ? s[t - off] : 0;
        __syncthreads();
        s[t] += add;
        __syncthreads();
    }
    if (i < n) offs[i] = s[t] - v;
    if (t == 255) bsum[blockIdx.x] = s[255];
}

__global__ __launch_bounds__(256) void k_scan2(int* __restrict__ bsum, int nb) {
    __shared__ int s[256];
    __shared__ int carry;
    int t = threadIdx.x;
    if (t == 0) carry = 0;
    __syncthreads();
    for (int base = 0; base < nb; base += 256) {
        int i = base + t;
        int v = (i < nb) ? bsum[i] : 0;
        s[t] = v;
        __syncthreads();
        for (int off = 1; off < 256; off <<= 1) {
            int add = (t >= off) ? s[t - off] : 0;
            __syncthreads();
            s[t] += add;
            __syncthreads();
        }
        if (i < nb) bsum[i] = s[t] - v + carry;
        __syncthreads();
        if (t == 0) carry += s[255];
        __syncthreads();
    }
}

__global__ void k_scan3(int* __restrict__ offs, const int* __restrict__ bsum,
                        int n, int E) {
    int i = blockIdx.x * blockDim.x + threadIdx.x;
    if (i < n) offs[i] += bsum[i >> 8];
    if (i == 0) offs[n] = E;
}

// ---------------- bf16x3 MFMA GEMM body (f32 A), B staged in LDS ----------
template <int SPLITC>
__device__ void mfma_body(const float* __restrict__ A,
                          const __bf16* __restrict__ Wthi,
                          const __bf16* __restrict__ Wtlo,
                          __bf16* __restrict__ Cl, float* __restrict__ Cr,
                          int M, int bid) {
    constexpr int K = 128;
    __shared__ __bf16 sB[2][128][40];     // 20 KB
    const int tid = threadIdx.x;
    const int lane = tid & 63;
    const int wave = tid >> 6;
    const int row0 = bid * 128 + wave * 32;
    const int rlo = lane & 15;
    const int rhi = lane >> 4;

    const int sc = tid >> 1;
    const int sseg = (tid & 1) * 16;

    f32x4 acc[4][2][2] = {};

    for (int k0 = 0; k0 < K; k0 += 32) {
        if (k0) __syncthreads();
        {
            const __bf16* gh = Wthi + (size_t)sc * K + k0 + sseg;
            const __bf16* gl = Wtlo + (size_t)sc * K + k0 + sseg;
            *(bf16x8*)(&sB[0][sc][sseg])     = *(const bf16x8*)gh;
            *(bf16x8*)(&sB[0][sc][sseg + 8]) = *(const bf16x8*)(gh + 8);
            *(bf16x8*)(&sB[1][sc][sseg])     = *(const bf16x8*)gl;
            *(bf16x8*)(&sB[1][sc][sseg + 8]) = *(const bf16x8*)(gl + 8);
        }
        bf16x8 ahi[2], alo[2];
        #pragma unroll
        for (int wr = 0; wr < 2; ++wr) {
            int row = row0 + wr * 16 + rlo;
            row = row < M ? row : M - 1;
            const float* ap = A + (size_t)row * K + k0 + rhi * 8;
            float4 v0 = *(const float4*)ap;
            float4 v1 = *(const float4*)(ap + 4);
            float vv[8] = {v0.x, v0.y, v0.z, v0.w, v1.x, v1.y, v1.z, v1.w};
            #pragma unroll
            for (int i = 0; i < 8; ++i) {
                __bf16 h = (__bf16)vv[i];
                ahi[wr][i] = h;
                alo[wr][i] = (__bf16)(vv[i] - (float)h);
            }
        }
        __syncthreads();
        #pragma unroll
        for (int cs = 0; cs < 4; ++cs) {
            #pragma unroll
            for (int cf = 0; cf < 2; ++cf) {
                int c = cs * 32 + cf * 16 + rlo;
                bf16x8 bhi = *(const bf16x8*)(&sB[0][c][rhi * 8]);
                bf16x8 blo = *(const bf16x8*)(&sB[1][c][rhi * 8]);
                #pragma unroll
                for (int wr = 0; wr < 2; ++wr) {
                    f32x4 a = acc[cs][wr][cf];
                    a = __builtin_amdgcn_mfma_f32_16x16x32_bf16(ahi[wr], bhi, a, 0, 0, 0);
                    a = __builtin_amdgcn_mfma_f32_16x16x32_bf16(ahi[wr], blo, a, 0, 0, 0);
                    a = __builtin_amdgcn_mfma_f32_16x16x32_bf16(alo[wr], bhi, a, 0, 0, 0);
                    acc[cs][wr][cf] = a;
                }
            }
        }
    }

    #pragma unroll
    for (int cs = 0; cs < 4; ++cs)
        #pragma unroll
        for (int cf = 0; cf < 2; ++cf) {
            int c = cs * 32 + cf * 16 + rlo;
            #pragma unroll
            for (int wr = 0; wr < 2; ++wr)
                #pragma unroll
                for (int r = 0; r < 4; ++r) {
                    int row = row0 + wr * 16 + rhi * 4 + r;
                    if (row < M) {
                        float val = acc[cs][wr][cf][r];
                        if (c < SPLITC)
                            Cl[(size_t)row * SPLITC + c] = (__bf16)val;
                        else
                            Cr[(size_t)row * (128 - SPLITC) + (c - SPLITC)] = val;
                    }
                }
        }
}

// layer-2 GEMM: A is bf16 (exact) -> only 2 MFMAs per step
__global__ __launch_bounds__(256) void k_mfma2(const __bf16* __restrict__ A,
                                               const __bf16* __restrict__ Wthi,
                                               const __bf16* __restrict__ Wtlo,
                                               __bf16* __restrict__ Cl,
                                               float* __restrict__ Cr, int M) {
    constexpr int K = 128;
    constexpr int SPLITC = 64;
    __shared__ __bf16 sB[2][128][40];
    const int tid = threadIdx.x;
    const int lane = tid & 63;
    const int wave = tid >> 6;
    const int row0 = blockIdx.x * 128 + wave * 32;
    const int rlo = lane & 15;
    const int rhi = lane >> 4;
    const int sc = tid >> 1;
    const int sseg = (tid & 1) * 16;

    f32x4 acc[4][2][2] = {};

    for (int k0 = 0; k0 < K; k0 += 32) {
        if (k0) __syncthreads();
        {
            const __bf16* gh = Wthi + (size_t)sc * K + k0 + sseg;
            const __bf16* gl = Wtlo + (size_t)sc * K + k0 + sseg;
            *(bf16x8*)(&sB[0][sc][sseg])     = *(const bf16x8*)gh;
            *(bf16x8*)(&sB[0][sc][sseg + 8]) = *(const bf16x8*)(gh + 8);
            *(bf16x8*)(&sB[1][sc][sseg])     = *(const bf16x8*)gl;
            *(bf16x8*)(&sB[1][sc][sseg + 8]) = *(const bf16x8*)(gl + 8);
        }
        bf16x8 a[2];
        #pragma unroll
        for (int wr = 0; wr < 2; ++wr) {
            int row = row0 + wr * 16 + rlo;
            row = row < M ? row : M - 1;
            a[wr] = *(const bf16x8*)(A + (size_t)row * K + k0 + rhi * 8);
        }
        __syncthreads();
        #pragma unroll
        for (int cs = 0; cs < 4; ++cs) {
            #pragma unroll
            for (int cf = 0; cf < 2; ++cf) {
                int c = cs * 32 + cf * 16 + rlo;
                bf16x8 bhi = *(const bf16x8*)(&sB[0][c][rhi * 8]);
                bf16x8 blo = *(const bf16x8*)(&sB[1][c][rhi * 8]);
                #pragma unroll
                for (int wr = 0; wr < 2; ++wr) {
                    f32x4 v = acc[cs][wr][cf];
                    v = __builtin_amdgcn_mfma_f32_16x16x32_bf16(a[wr], bhi, v, 0, 0, 0);
                    v = __builtin_amdgcn_mfma_f32_16x16x32_bf16(a[wr], blo, v, 0, 0, 0);
                    acc[cs][wr][cf] = v;
                }
            }
        }
    }

    #pragma unroll
    for (int cs = 0; cs < 4; ++cs)
        #pragma unroll
        for (int cf = 0; cf < 2; ++cf) {
            int c = cs * 32 + cf * 16 + rlo;
            #pragma unroll
            for (int wr = 0; wr < 2; ++wr)
                #pragma unroll
                for (int r = 0; r < 4; ++r) {
                    int row = row0 + wr * 16 + rhi * 4 + r;
                    if (row < M) {
                        float val = acc[cs][wr][cf][r];
                        if (c < SPLITC)
                            Cl[(size_t)row * SPLITC + c] = (__bf16)val;
                        else
                            Cr[(size_t)row * (128 - SPLITC) + (c - SPLITC)] = val;
                    }
                }
        }
}

// fused layer-1 GEMM (two 128-col halves) + CSR scatter (4 edges/thread)
__global__ __launch_bounds__(256) void k_mfma_bin(const float* __restrict__ A,
                                                  const __bf16* __restrict__ Wthi,
                                                  const __bf16* __restrict__ Wtlo,
                                                  __bf16* __restrict__ Cl,
                                                  float* __restrict__ Cr, int M,
                                                  int G,
                                                  const int* __restrict__ idx32,
                                                  const int* __restrict__ rank,
                                                  const int* __restrict__ offs,
                                                  int* __restrict__ csr, int E) {
    int bid = blockIdx.x;
    if (bid < G) {
        mfma_body<128>(A, Wthi, Wtlo, Cl, nullptr, M, bid);
        return;
    }
    bid -= G;
    if (bid < G) {
        mfma_body<0>(A, Wthi + 128 * 128, Wtlo + 128 * 128, nullptr, Cr, M, bid);
        return;
    }
    bid -= G;
    int base = bid * 1024 + threadIdx.x;
    #pragma unroll
    for (int k = 0; k < 4; ++k) {
        int e = base + k * 256;
        if (e < E) {
            int d = idx32[E + e];
            csr[offs[d] + rank[e]] = idx32[e];
        }
    }
}

// ---------------- fused gather(bf16) + mean + lin_r + BN(affine) + ReLU ----
// one wave per node; 16 lanes per row; BN as y = (sx*inv + lin)*S + T.
// F=128 -> bf16 out (packed uint4); F=64 -> f32 out (float4).
template <int LOGF>
__global__ __launch_bounds__(256) void k_agg(const __bf16* __restrict__ xl,
                                             const float* __restrict__ lin,
                                             const int* __restrict__ csr,
                                             const int* __restrict__ offs,
                                             const float* __restrict__ S,
                                             const float* __restrict__ T,
                                             void* __restrict__ out, int N) {
    constexpr int F = 1 << LOGF;
    constexpr int NW = (F == 128) ? 8 : 4;
    int node = blockIdx.x * 4 + (threadIdx.x >> 6);
    if (node >= N) return;
    int lane = threadIdx.x & 63;
    int sub = lane >> 4;
    int col = lane & 15;
    int beg = offs[node], end = offs[node + 1];
    float inv = 1.0f / fmaxf((float)(end - beg), 1.0f);

    float sx[NW];
    #pragma unroll
    for (int j = 0; j < NW; ++j) sx[j] = 0.f;

    int e = beg;
    while (e < end) {
        int bl = min(64, end - e);
        int myidx = (lane < bl) ? csr[e + lane] : 0;
        int u = 0;
        for (; u + 8 <= bl; u += 8) {
            int s0 = __shfl(myidx, u + sub, 64);
            int s1 = __shfl(myidx, u + 4 + sub, 64);
            if constexpr (F == 128) {
                uint4 t0 = *(const uint4*)((const char*)xl + (size_t)s0 * 256 + col * 16);
                uint4 t1 = *(const uint4*)((const char*)xl + (size_t)s1 * 256 + col * 16);
                unsigned int w0[4] = {t0.x, t0.y, t0.z, t0.w};
                unsigned int w1[4] = {t1.x, t1.y, t1.z, t1.w};
                #pragma unroll
                for (int i = 0; i < 4; ++i) {
                    sx[2 * i]     += __uint_as_float(w0[i] << 16) + __uint_as_float(w1[i] << 16);
                    sx[2 * i + 1] += __uint_as_float(w0[i] & 0xffff0000u) + __uint_as_float(w1[i] & 0xffff0000u);
                }
            } else {
                uint2 t0 = *(const uint2*)((const char*)xl + (size_t)s0 * 128 + col * 8);
                uint2 t1 = *(const uint2*)((const char*)xl + (size_t)s1 * 128 + col * 8);
                unsigned int w0[2] = {t0.x, t0.y};
                unsigned int w1[2] = {t1.x, t1.y};
                #pragma unroll
                for (int i = 0; i < 2; ++i) {
                    sx[2 * i]     += __uint_as_float(w0[i] << 16) + __uint_as_float(w1[i] << 16);
                    sx[2 * i + 1] += __uint_as_float(w0[i] & 0xffff0000u) + __uint_as_float(w1[i] & 0xffff0000u);
                }
            }
        }
        for (; u + 4 <= bl; u += 4) {
            int s0 = __shfl(myidx, u + sub, 64);
            if constexpr (F == 128) {
                uint4 t0 = *(const uint4*)((const char*)xl + (size_t)s0 * 256 + col * 16);
                unsigned int w0[4] = {t0.x, t0.y, t0.z, t0.w};
                #pragma unroll
                for (int i = 0; i < 4; ++i) {
                    sx[2 * i]     += __uint_as_float(w0[i] << 16);
                    sx[2 * i + 1] += __uint_as_float(w0[i] & 0xffff0000u);
                }
            } else {
                uint2 t0 = *(const uint2*)((const char*)xl + (size_t)s0 * 128 + col * 8);
                unsigned int w0[2] = {t0.x, t0.y};
                #pragma unroll
                for (int i = 0; i < 2; ++i) {
                    sx[2 * i]     += __uint_as_float(w0[i] << 16);
                    sx[2 * i + 1] += __uint_as_float(w0[i] & 0xffff0000u);
                }
            }
        }
        if (u < bl) {
            int rr = u + sub;
            int s0 = __shfl(myidx, rr < bl ? rr : u, 64);
            bool ok = rr < bl;
            if constexpr (F == 128) {
                uint4 t0 = *(const uint4*)((const char*)xl + (size_t)s0 * 256 + col * 16);
                unsigned int w0[4] = {t0.x, t0.y, t0.z, t0.w};
                #pragma unroll
                for (int i = 0; i < 4; ++i) {
                    sx[2 * i]     += ok ? __uint_as_float(w0[i] << 16) : 0.f;
                    sx[2 * i + 1] += ok ? __uint_as_float(w0[i] & 0xffff0000u) : 0.f;
                }
            } else {
                uint2 t0 = *(const uint2*)((const char*)xl + (size_t)s0 * 128 + col * 8);
                unsigned int w0[2] = {t0.x, t0.y};
                #pragma unroll
                for (int i = 0; i < 2; ++i) {
                    sx[2 * i]     += ok ? __uint_as_float(w0[i] << 16) : 0.f;
                    sx[2 * i + 1] += ok ? __uint_as_float(w0[i] & 0xffff0000u) : 0.f;
                }
            }
        }
        e += bl;
    }

    #pragma unroll
    for (int j = 0; j < NW; ++j) {
        sx[j] += __shfl_xor(sx[j], 16, 64);
        sx[j] += __shfl_xor(sx[j], 32, 64);
    }

    if (sub == 0) {
        if constexpr (F == 128) {
            const float4* lp = (const float4*)(lin + (size_t)node * 128 + col * 8);
            float4 l0 = lp[0], l1 = lp[1];
            const float4* Sp = (const float4*)(S + col * 8);
            const float4* Tp = (const float4*)(T + col * 8);
            float4 Sa = Sp[0], Sb = Sp[1], Ta = Tp[0], Tb = Tp[1];
            float lv[8] = {l0.x, l0.y, l0.z, l0.w, l1.x, l1.y, l1.z, l1.w};
            float Sv[8] = {Sa.x, Sa.y, Sa.z, Sa.w, Sb.x, Sb.y, Sb.z, Sb.w};
            float Tv[8] = {Ta.x, Ta.y, Ta.z, Ta.w, Tb.x, Tb.y, Tb.z, Tb.w};
            unsigned int u[4];
            #pragma unroll
            for (int i = 0; i < 4; ++i) {
                float y0 = fmaxf(fmaf(fmaf(sx[2 * i], inv, lv[2 * i]), Sv[2 * i], Tv[2 * i]), 0.f);
                float y1 = fmaxf(fmaf(fmaf(sx[2 * i + 1], inv, lv[2 * i + 1]), Sv[2 * i + 1], Tv[2 * i + 1]), 0.f);
                u[i] = pk2(y0, y1);
            }
            *(uint4*)((char*)out + (size_t)node * 256 + col * 16) = make_uint4(u[0], u[1], u[2], u[3]);
        } else {
            float4 l = *(const float4*)(lin + (size_t)node * 64 + col * 4);
            float4 Sv = *(const float4*)(S + col * 4);
            float4 Tv = *(const float4*)(T + col * 4);
            float4 o;
            o.x = fmaxf(fmaf(fmaf(sx[0], inv, l.x), Sv.x, Tv.x), 0.f);
            o.y = fmaxf(fmaf(fmaf(sx[1], inv, l.y), Sv.y, Tv.y), 0.f);
            o.z = fmaxf(fmaf(fmaf(sx[2], inv, l.z), Sv.z, Tv.z), 0.f);
            o.w = fmaxf(fmaf(fmaf(sx[3], inv, l.w), Sv.w, Tv.w), 0.f);
            *(float4*)((float*)out + (size_t)node * 64 + col * 4) = o;
        }
    }
}

// ---------------- head ----------------
__global__ __launch_bounds__(256) void k_head(const float* __restrict__ h2,
                                              const float* __restrict__ Wh,
                                              const float* __restrict__ bh,
                                              float* __restrict__ out, int M) {
    __shared__ float sW[64 * 10];
    __shared__ float sb[10];
    for (int i = threadIdx.x; i < 640; i += 256) sW[i] = Wh[i];
    if (threadIdx.x < 10) sb[threadIdx.x] = bh[threadIdx.x];
    __syncthreads();
    int n = blockIdx.x * blockDim.x + threadIdx.x;
    if (n >= M) return;
    float acc[10];
    #pragma unroll
    for (int c = 0; c < 10; ++c) acc[c] = sb[c];
    const float* hr = h2 + (size_t)n * 64;
    #pragma unroll
    for (int k = 0; k < 64; ++k) {
        float hv = hr[k];
        #pragma unroll
        for (int c = 0; c < 10; ++c) acc[c] = fmaf(hv, sW[k * 10 + c], acc[c]);
    }
    #pragma unroll
    for (int c = 0; c < 10; ++c) out[(size_t)n * 10 + c] = acc[c];
}

// ---------------------------------------------------------------------------
static inline size_t align256(size_t x) { return (x + 255) & ~(size_t)255; }

extern "C" void kernel_launch(void* const* d_in, const int* in_sizes, int n_in,
                              void* d_out, int out_size, void* d_ws, size_t ws_size,
                              hipStream_t stream) {
    const float* x   = (const float*)d_in[0];
    const void*  ei  = d_in[1];
    const float* W1l = (const float*)d_in[2];
    const float* b1l = (const float*)d_in[3];
    const float* W1r = (const float*)d_in[4];
    const float* g1  = (const float*)d_in[5];
    const float* be1 = (const float*)d_in[6];
    const float* m1  = (const float*)d_in[7];
    const float* v1  = (const float*)d_in[8];
    const float* W2l = (const float*)d_in[9];
    const float* b2l = (const float*)d_in[10];
    const float* W2r = (const float*)d_in[11];
    const float* g2  = (const float*)d_in[12];
    const float* be2 = (const float*)d_in[13];
    const float* m2  = (const float*)d_in[14];
    const float* v2  = (const float*)d_in[15];
    const float* Wh  = (const float*)d_in[16];
    const float* bh  = (const float*)d_in[17];
    float* out = (float*)d_out;

    const int N = N_NODES;
    const int E = in_sizes[1] / 2;
    const int NB = (N + 255) / 256;

    // -------- workspace layout --------
    char* p = (char*)d_ws;
    int* idx32 = (int*)p;  p += align256((size_t)2 * E * 4);
    int* rank  = (int*)p;  p += align256((size_t)E * 4);
    int* csr   = (int*)p;  p += align256((size_t)E * 4);
    int* offs  = (int*)p;  p += align256((size_t)(N + 1) * 4);
    int* deg   = (int*)p;  p += align256((size_t)N * 64);      // 64 B / node
    int* bsum  = (int*)p;  p += 4096;
    float* bn  = (float*)p; p += 4096;   // S1[128] T1[128] S2[64] T2[64]
    __bf16* Wt1hi = (__bf16*)p; p += align256((size_t)256 * 128 * 2);
    __bf16* Wt1lo = (__bf16*)p; p += align256((size_t)256 * 128 * 2);
    __bf16* Wt2hi = (__bf16*)p; p += align256((size_t)128 * 128 * 2);
    __bf16* Wt2lo = (__bf16*)p; p += align256((size_t)128 * 128 * 2);
    __bf16* xl = (__bf16*)p; p += align256((size_t)N * 128 * 2);
    float* xr  = (float*)p;  p += (size_t)N * 128 * 4;
    __bf16* hb = (__bf16*)p; p += align256((size_t)N * 128 * 2);
    // layer-2 reuse
    __bf16* t2l = xl;                    // [N,64] bf16
    float* t2r  = xr;                    // [N,64] f32
    float* h2   = (float*)hb;            // [N,64] f32 (hb dead after mfma2)

    dim3 blk(256);
    const int WPB = (2 * 128 * 128 + 2 * 64 * 128 + 255) / 256;   // 192
    int prepB = (E + 255) / 256;
    int G = (N + 127) / 128;
    int binBlocks = (E + 1023) / 1024;

    // -------- fused weight/BN/edge prep (low VGPR, padded deg) --------
    hipMemsetAsync(deg, 0, (size_t)N * 64, stream);
    k_prep<<<dim3(WPB + 1 + prepB), blk, 0, stream>>>(
        (const unsigned int*)ei, E, idx32, rank, deg, WPB,
        W1l, W1r, W2l, W2r, Wt1hi, Wt1lo, Wt2hi, Wt2lo,
        b1l, g1, be1, m1, v1, b2l, g2, be2, m2, v2, bn);

    // -------- scans --------
    k_scan1<<<dim3(NB), blk, 0, stream>>>(deg, offs, bsum, N);
    k_scan2<<<dim3(1), blk, 0, stream>>>(bsum, NB);
    k_scan3<<<dim3(NB), blk, 0, stream>>>(offs, bsum, N, E);

    // -------- layer-1 GEMM (two halves, LDS-staged B) + scatter --------
    k_mfma_bin<<<dim3(2 * G + binBlocks), blk, 0, stream>>>(
        x, Wt1hi, Wt1lo, xl, xr, N, G, idx32, rank, offs, csr, E);

    // -------- layer 1 aggregate (bf16 out) --------
    k_agg<7><<<dim3((N + 3) / 4), blk, 0, stream>>>(
        xl, xr, csr, offs, bn, bn + 128, hb, N);

    // -------- layer 2 (bf16 A) --------
    k_mfma2<<<dim3(G), blk, 0, stream>>>(hb, Wt2hi, Wt2lo, t2l, t2r, N);
    k_agg<6><<<dim3((N + 3) / 4), blk, 0, stream>>>(
        t2l, t2r, csr, offs, bn + 256, bn + 320, h2, N);

    // -------- head --------
    k_head<<<dim3((N + 255) / 256), blk, 0, stream>>>(h2, Wh, bh, out, N);
}

// Round 15
// 275.270 us; speedup vs baseline: 1.0970x; 1.0267x over previous
//
#include <hip/hip_runtime.h>
#include <hip/hip_bf16.h>
#include <stdint.h>

#define N_NODES 100000
constexpr float BN_EPS = 1e-5f;

typedef __bf16 bf16x8 __attribute__((ext_vector_type(8)));
typedef float f32x4 __attribute__((ext_vector_type(4)));

__device__ inline unsigned int pk2(float a, float b) {
    __bf16 x = (__bf16)a, y = (__bf16)b;
    return (unsigned int)__builtin_bit_cast(unsigned short, x) |
           ((unsigned int)__builtin_bit_cast(unsigned short, y) << 16);
}

// ---------------- K0: weight prep + BN affine prep (tiny) ----------------
__global__ __launch_bounds__(256) void k_wbn(int wpB,
                                             const float* __restrict__ W1l,
                                             const float* __restrict__ W1r,
                                             const float* __restrict__ W2l,
                                             const float* __restrict__ W2r,
                                             __bf16* __restrict__ Wt1hi,
                                             __bf16* __restrict__ Wt1lo,
                                             __bf16* __restrict__ Wt2hi,
                                             __bf16* __restrict__ Wt2lo,
                                             const float* __restrict__ b1l,
                                             const float* __restrict__ g1,
                                             const float* __restrict__ be1,
                                             const float* __restrict__ m1,
                                             const float* __restrict__ v1,
                                             const float* __restrict__ b2l,
                                             const float* __restrict__ g2,
                                             const float* __restrict__ be2,
                                             const float* __restrict__ m2,
                                             const float* __restrict__ v2,
                                             float* __restrict__ bn) {
    if ((int)blockIdx.x < wpB) {
        int idx = blockIdx.x * 256 + threadIdx.x;
        const float* W; __bf16 *Whi, *Wlo; int halfN, lidx;
        if (idx < 2 * 128 * 128) {
            lidx = idx; halfN = 128; Whi = Wt1hi; Wlo = Wt1lo;
            W = ((lidx >> 7) < 128) ? W1l : W1r;
        } else {
            lidx = idx - 2 * 128 * 128;
            if (lidx >= 2 * 64 * 128) return;
            halfN = 64; Whi = Wt2hi; Wlo = Wt2lo;
            W = ((lidx >> 7) < 64) ? W2l : W2r;
        }
        int c = lidx >> 7, k = lidx & 127;
        int cc = (c < halfN) ? c : c - halfN;
        float v = W[(size_t)k * halfN + cc];
        __bf16 h = (__bf16)v;
        Whi[lidx] = h;
        Wlo[lidx] = (__bf16)(v - (float)h);
        return;
    }
    int t = threadIdx.x;
    if (t < 128) {                                   // layer-1 S/T
        float S = g1[t] * rsqrtf(v1[t] + BN_EPS);
        bn[t] = S;
        bn[128 + t] = (b1l[t] - m1[t]) * S + be1[t];
    } else if (t < 192) {                            // layer-2 S/T
        int f = t - 128;
        float S = g2[f] * rsqrtf(v2[f] + BN_EPS);
        bn[256 + f] = S;
        bn[320 + f] = (b2l[f] - m2[f]) * S + be2[f];
    }
}

// ---------------- bf16x3 MFMA GEMM body (f32 A), B staged in LDS ----------
template <int SPLITC>
__device__ void mfma_body(const float* __restrict__ A,
                          const __bf16* __restrict__ Wthi,
                          const __bf16* __restrict__ Wtlo,
                          __bf16* __restrict__ Cl, float* __restrict__ Cr,
                          int M, int bid) {
    constexpr int K = 128;
    __shared__ __bf16 sB[2][128][40];     // 20 KB
    const int tid = threadIdx.x;
    const int lane = tid & 63;
    const int wave = tid >> 6;
    const int row0 = bid * 128 + wave * 32;
    const int rlo = lane & 15;
    const int rhi = lane >> 4;

    const int sc = tid >> 1;
    const int sseg = (tid & 1) * 16;

    f32x4 acc[4][2][2] = {};

    for (int k0 = 0; k0 < K; k0 += 32) {
        if (k0) __syncthreads();
        {
            const __bf16* gh = Wthi + (size_t)sc * K + k0 + sseg;
            const __bf16* gl = Wtlo + (size_t)sc * K + k0 + sseg;
            *(bf16x8*)(&sB[0][sc][sseg])     = *(const bf16x8*)gh;
            *(bf16x8*)(&sB[0][sc][sseg + 8]) = *(const bf16x8*)(gh + 8);
            *(bf16x8*)(&sB[1][sc][sseg])     = *(const bf16x8*)gl;
            *(bf16x8*)(&sB[1][sc][sseg + 8]) = *(const bf16x8*)(gl + 8);
        }
        bf16x8 ahi[2], alo[2];
        #pragma unroll
        for (int wr = 0; wr < 2; ++wr) {
            int row = row0 + wr * 16 + rlo;
            row = row < M ? row : M - 1;
            const float* ap = A + (size_t)row * K + k0 + rhi * 8;
            float4 v0 = *(const float4*)ap;
            float4 v1 = *(const float4*)(ap + 4);
            float vv[8] = {v0.x, v0.y, v0.z, v0.w, v1.x, v1.y, v1.z, v1.w};
            #pragma unroll
            for (int i = 0; i < 8; ++i) {
                __bf16 h = (__bf16)vv[i];
                ahi[wr][i] = h;
                alo[wr][i] = (__bf16)(vv[i] - (float)h);
            }
        }
        __syncthreads();
        #pragma unroll
        for (int cs = 0; cs < 4; ++cs) {
            #pragma unroll
            for (int cf = 0; cf < 2; ++cf) {
                int c = cs * 32 + cf * 16 + rlo;
                bf16x8 bhi = *(const bf16x8*)(&sB[0][c][rhi * 8]);
                bf16x8 blo = *(const bf16x8*)(&sB[1][c][rhi * 8]);
                #pragma unroll
                for (int wr = 0; wr < 2; ++wr) {
                    f32x4 a = acc[cs][wr][cf];
                    a = __builtin_amdgcn_mfma_f32_16x16x32_bf16(ahi[wr], bhi, a, 0, 0, 0);
                    a = __builtin_amdgcn_mfma_f32_16x16x32_bf16(ahi[wr], blo, a, 0, 0, 0);
                    a = __builtin_amdgcn_mfma_f32_16x16x32_bf16(alo[wr], bhi, a, 0, 0, 0);
                    acc[cs][wr][cf] = a;
                }
            }
        }
    }

    #pragma unroll
    for (int cs = 0; cs < 4; ++cs)
        #pragma unroll
        for (int cf = 0; cf < 2; ++cf) {
            int c = cs * 32 + cf * 16 + rlo;
            #pragma unroll
            for (int wr = 0; wr < 2; ++wr)
                #pragma unroll
                for (int r = 0; r < 4; ++r) {
                    int row = row0 + wr * 16 + rhi * 4 + r;
                    if (row < M) {
                        float val = acc[cs][wr][cf][r];
                        if (c < SPLITC)
                            Cl[(size_t)row * SPLITC + c] = (__bf16)val;
                        else
                            Cr[(size_t)row * (128 - SPLITC) + (c - SPLITC)] = val;
                    }
                }
        }
}

// ---------------- K1: persistent edge-prep blocks + layer-1 GEMM half1 ----
// 512 prep blocks (each ~3125 edges, looped) issue the atomic stream while
// GEMM blocks stream MFMA alongside for the whole atomic-limited window.
__global__ __launch_bounds__(256) void k_prep_gemm(const unsigned int* __restrict__ w,
                                                   int E, int* __restrict__ idx32,
                                                   int* __restrict__ rank,
                                                   int* __restrict__ deg,
                                                   int prepB, int chunk,
                                                   const float* __restrict__ A,
                                                   const __bf16* __restrict__ Wthi,
                                                   const __bf16* __restrict__ Wtlo,
                                                   __bf16* __restrict__ Cl, int M) {
    int bid = blockIdx.x;
    if (bid < prepB) {
        unsigned int wv = w[1 + 2 * (threadIdx.x & 63)];
        int f = __any(wv != 0);        // 1 => int32, 0 => int64
        int lo = bid * chunk;
        int hi = min(lo + chunk, E);
        for (int e = lo + (int)threadIdx.x; e < hi; e += 256) {
            int s = (int)(f ? w[e] : w[2 * (size_t)e]);
            int d = (int)(f ? w[E + e] : w[2 * ((size_t)E + e)]);
            idx32[e] = s;
            idx32[E + e] = d;
            rank[e] = atomicAdd(&deg[d], 1);
        }
        return;
    }
    mfma_body<128>(A, Wthi, Wtlo, Cl, nullptr, M, bid - prepB);
}

// ---------------- scans ----------------
__global__ __launch_bounds__(256) void k_scan1(const int* __restrict__ deg,
                                               int* __restrict__ offs,
                                               int* __restrict__ bsum, int n) {
    __shared__ int s[256];
    int t = threadIdx.x;
    int i = blockIdx.x * 256 + t;
    int v = (i < n) ? deg[i] : 0;
    s[t] = v;
    __syncthreads();
    for (int off = 1; off < 256; off <<= 1) {
        int add = (t >= off) ? s[t - off] : 0;
        __syncthreads();
        s[t] += add;
        __syncthreads();
    }
    if (i < n) offs[i] = s[t] - v;
    if (t == 255) bsum[blockIdx.x] = s[255];
}

__global__ __launch_bounds__(256) void k_scan2(int* __restrict__ bsum, int nb) {
    __shared__ int s[256];
    __shared__ int carry;
    int t = threadIdx.x;
    if (t == 0) carry = 0;
    __syncthreads();
    for (int base = 0; base < nb; base += 256) {
        int i = base + t;
        int v = (i < nb) ? bsum[i] : 0;
        s[t] = v;
        __syncthreads();
        for (int off = 1; off < 256; off <<= 1) {
            int add = (t >= off) ? s[t - off] : 0;
            __syncthreads();
            s[t] += add;
            __syncthreads();
        }
        if (i < nb) bsum[i] = s[t] - v + carry;
        __syncthreads();
        if (t == 0) carry += s[255];
        __syncthreads();
    }
}

__global__ void k_scan3(int* __restrict__ offs, const int* __restrict__ bsum,
                        int n, int E) {
    int i = blockIdx.x * blockDim.x + threadIdx.x;
    if (i < n) offs[i] += bsum[i >> 8];
    if (i == 0) offs[n] = E;
}

// ---------------- K3: layer-1 GEMM half2 (f32 out) + CSR scatter ----------
__global__ __launch_bounds__(256) void k_gemm_scat(const float* __restrict__ A,
                                                   const __bf16* __restrict__ Wthi,
                                                   const __bf16* __restrict__ Wtlo,
                                                   float* __restrict__ Cr, int M,
                                                   int G,
                                                   const int* __restrict__ idx32,
                                                   const int* __restrict__ rank,
                                                   const int* __restrict__ offs,
                                                   int* __restrict__ csr, int E) {
    int bid = blockIdx.x;
    if (bid < G) {
        mfma_body<0>(A, Wthi, Wtlo, nullptr, Cr, M, bid);
        return;
    }
    bid -= G;
    int base = bid * 1024 + threadIdx.x;
    #pragma unroll
    for (int k = 0; k < 4; ++k) {
        int e = base + k * 256;
        if (e < E) {
            int d = idx32[E + e];
            csr[offs[d] + rank[e]] = idx32[e];
        }
    }
}

// layer-2 GEMM: A is bf16 (exact) -> only 2 MFMAs per step
__global__ __launch_bounds__(256) void k_mfma2(const __bf16* __restrict__ A,
                                               const __bf16* __restrict__ Wthi,
                                               const __bf16* __restrict__ Wtlo,
                                               __bf16* __restrict__ Cl,
                                               float* __restrict__ Cr, int M) {
    constexpr int K = 128;
    constexpr int SPLITC = 64;
    __shared__ __bf16 sB[2][128][40];
    const int tid = threadIdx.x;
    const int lane = tid & 63;
    const int wave = tid >> 6;
    const int row0 = blockIdx.x * 128 + wave * 32;
    const int rlo = lane & 15;
    const int rhi = lane >> 4;
    const int sc = tid >> 1;
    const int sseg = (tid & 1) * 16;

    f32x4 acc[4][2][2] = {};

    for (int k0 = 0; k0 < K; k0 += 32) {
        if (k0) __syncthreads();
        {
            const __bf16* gh = Wthi + (size_t)sc * K + k0 + sseg;
            const __bf16* gl = Wtlo + (size_t)sc * K + k0 + sseg;
            *(bf16x8*)(&sB[0][sc][sseg])     = *(const bf16x8*)gh;
            *(bf16x8*)(&sB[0][sc][sseg + 8]) = *(const bf16x8*)(gh + 8);
            *(bf16x8*)(&sB[1][sc][sseg])     = *(const bf16x8*)gl;
            *(bf16x8*)(&sB[1][sc][sseg + 8]) = *(const bf16x8*)(gl + 8);
        }
        bf16x8 a[2];
        #pragma unroll
        for (int wr = 0; wr < 2; ++wr) {
            int row = row0 + wr * 16 + rlo;
            row = row < M ? row : M - 1;
            a[wr] = *(const bf16x8*)(A + (size_t)row * K + k0 + rhi * 8);
        }
        __syncthreads();
        #pragma unroll
        for (int cs = 0; cs < 4; ++cs) {
            #pragma unroll
            for (int cf = 0; cf < 2; ++cf) {
                int c = cs * 32 + cf * 16 + rlo;
                bf16x8 bhi = *(const bf16x8*)(&sB[0][c][rhi * 8]);
                bf16x8 blo = *(const bf16x8*)(&sB[1][c][rhi * 8]);
                #pragma unroll
                for (int wr = 0; wr < 2; ++wr) {
                    f32x4 v = acc[cs][wr][cf];
                    v = __builtin_amdgcn_mfma_f32_16x16x32_bf16(a[wr], bhi, v, 0, 0, 0);
                    v = __builtin_amdgcn_mfma_f32_16x16x32_bf16(a[wr], blo, v, 0, 0, 0);
                    acc[cs][wr][cf] = v;
                }
            }
        }
    }

    #pragma unroll
    for (int cs = 0; cs < 4; ++cs)
        #pragma unroll
        for (int cf = 0; cf < 2; ++cf) {
            int c = cs * 32 + cf * 16 + rlo;
            #pragma unroll
            for (int wr = 0; wr < 2; ++wr)
                #pragma unroll
                for (int r = 0; r < 4; ++r) {
                    int row = row0 + wr * 16 + rhi * 4 + r;
                    if (row < M) {
                        float val = acc[cs][wr][cf][r];
                        if (c < SPLITC)
                            Cl[(size_t)row * SPLITC + c] = (__bf16)val;
                        else
                            Cr[(size_t)row * (128 - SPLITC) + (c - SPLITC)] = val;
                    }
                }
        }
}

// ---------------- fused gather(bf16) + mean + lin_r + BN(affine) + ReLU ----
template <int LOGF>
__global__ __launch_bounds__(256) void k_agg(const __bf16* __restrict__ xl,
                                             const float* __restrict__ lin,
                                             const int* __restrict__ csr,
                                             const int* __restrict__ offs,
                                             const float* __restrict__ S,
                                             const float* __restrict__ T,
                                             void* __restrict__ out, int N) {
    constexpr int F = 1 << LOGF;
    constexpr int NW = (F == 128) ? 8 : 4;
    int node = blockIdx.x * 4 + (threadIdx.x >> 6);
    if (node >= N) return;
    int lane = threadIdx.x & 63;
    int sub = lane >> 4;
    int col = lane & 15;
    int beg = offs[node], end = offs[node + 1];
    float inv = 1.0f / fmaxf((float)(end - beg), 1.0f);

    float sx[NW];
    #pragma unroll
    for (int j = 0; j < NW; ++j) sx[j] = 0.f;

    int e = beg;
    while (e < end) {
        int bl = min(64, end - e);
        int myidx = (lane < bl) ? csr[e + lane] : 0;
        int u = 0;
        for (; u + 8 <= bl; u += 8) {
            int s0 = __shfl(myidx, u + sub, 64);
            int s1 = __shfl(myidx, u + 4 + sub, 64);
            if constexpr (F == 128) {
                uint4 t0 = *(const uint4*)((const char*)xl + (size_t)s0 * 256 + col * 16);
                uint4 t1 = *(const uint4*)((const char*)xl + (size_t)s1 * 256 + col * 16);
                unsigned int w0[4] = {t0.x, t0.y, t0.z, t0.w};
                unsigned int w1[4] = {t1.x, t1.y, t1.z, t1.w};
                #pragma unroll
                for (int i = 0; i < 4; ++i) {
                    sx[2 * i]     += __uint_as_float(w0[i] << 16) + __uint_as_float(w1[i] << 16);
                    sx[2 * i + 1] += __uint_as_float(w0[i] & 0xffff0000u) + __uint_as_float(w1[i] & 0xffff0000u);
                }
            } else {
                uint2 t0 = *(const uint2*)((const char*)xl + (size_t)s0 * 128 + col * 8);
                uint2 t1 = *(const uint2*)((const char*)xl + (size_t)s1 * 128 + col * 8);
                unsigned int w0[2] = {t0.x, t0.y};
                unsigned int w1[2] = {t1.x, t1.y};
                #pragma unroll
                for (int i = 0; i < 2; ++i) {
                    sx[2 * i]     += __uint_as_float(w0[i] << 16) + __uint_as_float(w1[i] << 16);
                    sx[2 * i + 1] += __uint_as_float(w0[i] & 0xffff0000u) + __uint_as_float(w1[i] & 0xffff0000u);
                }
            }
        }
        for (; u + 4 <= bl; u += 4) {
            int s0 = __shfl(myidx, u + sub, 64);
            if constexpr (F == 128) {
                uint4 t0 = *(const uint4*)((const char*)xl + (size_t)s0 * 256 + col * 16);
                unsigned int w0[4] = {t0.x, t0.y, t0.z, t0.w};
                #pragma unroll
                for (int i = 0; i < 4; ++i) {
                    sx[2 * i]     += __uint_as_float(w0[i] << 16);
                    sx[2 * i + 1] += __uint_as_float(w0[i] & 0xffff0000u);
                }
            } else {
                uint2 t0 = *(const uint2*)((const char*)xl + (size_t)s0 * 128 + col * 8);
                unsigned int w0[2] = {t0.x, t0.y};
                #pragma unroll
                for (int i = 0; i < 2; ++i) {
                    sx[2 * i]     += __uint_as_float(w0[i] << 16);
                    sx[2 * i + 1] += __uint_as_float(w0[i] & 0xffff0000u);
                }
            }
        }
        if (u < bl) {
            int rr = u + sub;
            int s0 = __shfl(myidx, rr < bl ? rr : u, 64);
            bool ok = rr < bl;
            if constexpr (F == 128) {
                uint4 t0 = *(const uint4*)((const char*)xl + (size_t)s0 * 256 + col * 16);
                unsigned int w0[4] = {t0.x, t0.y, t0.z, t0.w};
                #pragma unroll
                for (int i = 0; i < 4; ++i) {
                    sx[2 * i]     += ok ? __uint_as_float(w0[i] << 16) : 0.f;
                    sx[2 * i + 1] += ok ? __uint_as_float(w0[i] & 0xffff0000u) : 0.f;
                }
            } else {
                uint2 t0 = *(const uint2*)((const char*)xl + (size_t)s0 * 128 + col * 8);
                unsigned int w0[2] = {t0.x, t0.y};
                #pragma unroll
                for (int i = 0; i < 2; ++i) {
                    sx[2 * i]     += ok ? __uint_as_float(w0[i] << 16) : 0.f;
                    sx[2 * i + 1] += ok ? __uint_as_float(w0[i] & 0xffff0000u) : 0.f;
                }
            }
        }
        e += bl;
    }

    #pragma unroll
    for (int j = 0; j < NW; ++j) {
        sx[j] += __shfl_xor(sx[j], 16, 64);
        sx[j] += __shfl_xor(sx[j], 32, 64);
    }

    if (sub == 0) {
        if constexpr (F == 128) {
            const float4* lp = (const float4*)(lin + (size_t)node * 128 + col * 8);
            float4 l0 = lp[0], l1 = lp[1];
            const float4* Sp = (const float4*)(S + col * 8);
            const float4* Tp = (const float4*)(T + col * 8);
            float4 Sa = Sp[0], Sb = Sp[1], Ta = Tp[0], Tb = Tp[1];
            float lv[8] = {l0.x, l0.y, l0.z, l0.w, l1.x, l1.y, l1.z, l1.w};
            float Sv[8] = {Sa.x, Sa.y, Sa.z, Sa.w, Sb.x, Sb.y, Sb.z, Sb.w};
            float Tv[8] = {Ta.x, Ta.y, Ta.z, Ta.w, Tb.x, Tb.y, Tb.z, Tb.w};
            unsigned int u[4];
            #pragma unroll
            for (int i = 0; i < 4; ++i) {
                float y0 = fmaxf(fmaf(fmaf(sx[2 * i], inv, lv[2 * i]), Sv[2 * i], Tv[2 * i]), 0.f);
                float y1 = fmaxf(fmaf(fmaf(sx[2 * i + 1], inv, lv[2 * i + 1]), Sv[2 * i + 1], Tv[2 * i + 1]), 0.f);
                u[i] = pk2(y0, y1);
            }
            *(uint4*)((char*)out + (size_t)node * 256 + col * 16) = make_uint4(u[0], u[1], u[2], u[3]);
        } else {
            float4 l = *(const float4*)(lin + (size_t)node * 64 + col * 4);
            float4 Sv = *(const float4*)(S + col * 4);
            float4 Tv = *(const float4*)(T + col * 4);
            float4 o;
            o.x = fmaxf(fmaf(fmaf(sx[0], inv, l.x), Sv.x, Tv.x), 0.f);
            o.y = fmaxf(fmaf(fmaf(sx[1], inv, l.y), Sv.y, Tv.y), 0.f);
            o.z = fmaxf(fmaf(fmaf(sx[2], inv, l.z), Sv.z, Tv.z), 0.f);
            o.w = fmaxf(fmaf(fmaf(sx[3], inv, l.w), Sv.w, Tv.w), 0.f);
            *(float4*)((float*)out + (size_t)node * 64 + col * 4) = o;
        }
    }
}

// ---------------- head ----------------
__global__ __launch_bounds__(256) void k_head(const float* __restrict__ h2,
                                              const float* __restrict__ Wh,
                                              const float* __restrict__ bh,
                                              float* __restrict__ out, int M) {
    __shared__ float sW[64 * 10];
    __shared__ float sb[10];
    for (int i = threadIdx.x; i < 640; i += 256) sW[i] = Wh[i];
    if (threadIdx.x < 10) sb[threadIdx.x] = bh[threadIdx.x];
    __syncthreads();
    int n = blockIdx.x * blockDim.x + threadIdx.x;
    if (n >= M) return;
    float acc[10];
    #pragma unroll
    for (int c = 0; c < 10; ++c) acc[c] = sb[c];
    const float* hr = h2 + (size_t)n * 64;
    #pragma unroll
    for (int k = 0; k < 64; ++k) {
        float hv = hr[k];
        #pragma unroll
        for (int c = 0; c < 10; ++c) acc[c] = fmaf(hv, sW[k * 10 + c], acc[c]);
    }
    #pragma unroll
    for (int c = 0; c < 10; ++c) out[(size_t)n * 10 + c] = acc[c];
}

// ---------------------------------------------------------------------------
static inline size_t align256(size_t x) { return (x + 255) & ~(size_t)255; }

extern "C" void kernel_launch(void* const* d_in, const int* in_sizes, int n_in,
                              void* d_out, int out_size, void* d_ws, size_t ws_size,
                              hipStream_t stream) {
    const float* x   = (const float*)d_in[0];
    const void*  ei  = d_in[1];
    const float* W1l = (const float*)d_in[2];
    const float* b1l = (const float*)d_in[3];
    const float* W1r = (const float*)d_in[4];
    const float* g1  = (const float*)d_in[5];
    const float* be1 = (const float*)d_in[6];
    const float* m1  = (const float*)d_in[7];
    const float* v1  = (const float*)d_in[8];
    const float* W2l = (const float*)d_in[9];
    const float* b2l = (const float*)d_in[10];
    const float* W2r = (const float*)d_in[11];
    const float* g2  = (const float*)d_in[12];
    const float* be2 = (const float*)d_in[13];
    const float* m2  = (const float*)d_in[14];
    const float* v2  = (const float*)d_in[15];
    const float* Wh  = (const float*)d_in[16];
    const float* bh  = (const float*)d_in[17];
    float* out = (float*)d_out;

    const int N = N_NODES;
    const int E = in_sizes[1] / 2;
    const int NB = (N + 255) / 256;

    // -------- workspace layout --------
    char* p = (char*)d_ws;
    int* idx32 = (int*)p;  p += align256((size_t)2 * E * 4);
    int* rank  = (int*)p;  p += align256((size_t)E * 4);
    int* csr   = (int*)p;  p += align256((size_t)E * 4);
    int* offs  = (int*)p;  p += align256((size_t)(N + 1) * 4);
    int* deg   = (int*)p;  p += align256((size_t)N * 4);
    int* bsum  = (int*)p;  p += 4096;
    float* bn  = (float*)p; p += 4096;   // S1[128] T1[128] S2[64] T2[64]
    __bf16* Wt1hi = (__bf16*)p; p += align256((size_t)256 * 128 * 2);
    __bf16* Wt1lo = (__bf16*)p; p += align256((size_t)256 * 128 * 2);
    __bf16* Wt2hi = (__bf16*)p; p += align256((size_t)128 * 128 * 2);
    __bf16* Wt2lo = (__bf16*)p; p += align256((size_t)128 * 128 * 2);
    __bf16* xl = (__bf16*)p; p += align256((size_t)N * 128 * 2);
    float* xr  = (float*)p;  p += (size_t)N * 128 * 4;
    __bf16* hb = (__bf16*)p; p += align256((size_t)N * 128 * 2);
    // layer-2 reuse
    __bf16* t2l = xl;                    // [N,64] bf16
    float* t2r  = xr;                    // [N,64] f32
    float* h2   = (float*)hb;            // [N,64] f32 (hb dead after mfma2)

    dim3 blk(256);
    const int WPB = (2 * 128 * 128 + 2 * 64 * 128 + 255) / 256;   // 192
    int G = (N + 127) / 128;
    int binBlocks = (E + 1023) / 1024;
    const int prepB = 512;
    int chunk = (E + prepB - 1) / prepB;

    // -------- K0: weight/BN prep --------
    hipMemsetAsync(deg, 0, (size_t)N * 4, stream);
    k_wbn<<<dim3(WPB + 1), blk, 0, stream>>>(WPB,
        W1l, W1r, W2l, W2r, Wt1hi, Wt1lo, Wt2hi, Wt2lo,
        b1l, g1, be1, m1, v1, b2l, g2, be2, m2, v2, bn);

    // -------- K1: persistent edge-prep || GEMM half1 -> xl (bf16) --------
    k_prep_gemm<<<dim3(prepB + G), blk, 0, stream>>>(
        (const unsigned int*)ei, E, idx32, rank, deg, prepB, chunk,
        x, Wt1hi, Wt1lo, xl, N);

    // -------- scans --------
    k_scan1<<<dim3(NB), blk, 0, stream>>>(deg, offs, bsum, N);
    k_scan2<<<dim3(1), blk, 0, stream>>>(bsum, NB);
    k_scan3<<<dim3(NB), blk, 0, stream>>>(offs, bsum, N, E);

    // -------- K3: GEMM half2 -> xr (f32) || CSR scatter --------
    k_gemm_scat<<<dim3(G + binBlocks), blk, 0, stream>>>(
        x, Wt1hi + 128 * 128, Wt1lo + 128 * 128, xr, N, G,
        idx32, rank, offs, csr, E);

    // -------- layer 1 aggregate (bf16 out) --------
    k_agg<7><<<dim3((N + 3) / 4), blk, 0, stream>>>(
        xl, xr, csr, offs, bn, bn + 128, hb, N);

    // -------- layer 2 (bf16 A) --------
    k_mfma2<<<dim3(G), blk, 0, stream>>>(hb, Wt2hi, Wt2lo, t2l, t2r, N);
    k_agg<6><<<dim3((N + 3) / 4), blk, 0, stream>>>(
        t2l, t2r, csr, offs, bn + 256, bn + 320, h2, N);

    // -------- head --------
    k_head<<<dim3((N + 255) / 256), blk, 0, stream>>>(h2, Wh, bh, out, N);
}